// Round 1
// baseline (13199.829 us; speedup 1.0000x reference)
//
#include <hip/hip_runtime.h>

#define NB 32
#define TT 12
#define NN 512
#define HH 64
#define EE 10
#define CS 66   // column stride for inp/g1/g2 buffers (max C)

__device__ __forceinline__ float sigmoidf_(float x){ return 1.f/(1.f+expf(-x)); }

// ---------------- fold Chebyshev recombination into weights ----------------
// dst[(s*C+c)*O+o]: s=0: W0-W2 ; s=1: W1 ; s=2: 2*W2
__global__ void fold_w(const float* __restrict__ src, float* __restrict__ dst, int C, int O){
  int idx = blockIdx.x*256 + threadIdx.x;
  int total = 3*C*O;
  if (idx >= total) return;
  int o  = idx % O;
  int rc = idx / O;
  int c  = rc % C;
  int s  = rc / C;
  float v;
  if (s == 0)      v = src[c*O+o] - src[(2*C+c)*O+o];
  else if (s == 1) v = src[(C+c)*O+o];
  else             v = 2.f*src[(2*C+c)*O+o];
  dst[idx] = v;
}

// ---------------- A = softmax(relu(E E^T)) per row ----------------
// grid = nb*NN blocks of 512 threads; one block per output row.
__global__ __launch_bounds__(512) void softmax_graph(
    const float* __restrict__ Emb, long long ebs, float* __restrict__ A, long long abs_)
{
  __shared__ float Es[NN*EE];
  __shared__ float red[8];
  int gid = blockIdx.x;
  int b = gid / NN;
  int n = gid % NN;
  const float* Eb = Emb + (long long)b*ebs;
  int tid = threadIdx.x;
  for (int i = tid; i < NN*EE; i += 512) Es[i] = Eb[i];
  __syncthreads();
  float q[EE];
  #pragma unroll
  for (int e = 0; e < EE; ++e) q[e] = Es[n*EE+e];
  int m = tid;
  float s = 0.f;
  #pragma unroll
  for (int e = 0; e < EE; ++e) s += q[e]*Es[m*EE+e];
  s = fmaxf(s, 0.f);
  int lane = tid & 63, wave = tid >> 6;
  float mx = s;
  #pragma unroll
  for (int off = 32; off >= 1; off >>= 1) mx = fmaxf(mx, __shfl_xor(mx, off, 64));
  if (lane == 0) red[wave] = mx;
  __syncthreads();
  mx = red[0];
  #pragma unroll
  for (int w = 1; w < 8; ++w) mx = fmaxf(mx, red[w]);
  float ev = expf(s - mx);
  float sm = ev;
  #pragma unroll
  for (int off = 32; off >= 1; off >>= 1) sm += __shfl_xor(sm, off, 64);
  __syncthreads();
  if (lane == 0) red[wave] = sm;
  __syncthreads();
  float tot = 0.f;
  #pragma unroll
  for (int w = 0; w < 8; ++w) tot += red[w];
  A[(long long)b*abs_ + (long long)n*NN + m] = ev / tot;
}

// ---------------- build inp buffer: [special cols | hidden-like cols] ----------------
__global__ void build_inp(const float* __restrict__ p0, long long bs0,
                          const float* __restrict__ p1, long long bs1,
                          const float* __restrict__ hm, float* __restrict__ inp,
                          int ns, int C)
{
  int idx = blockIdx.x*256 + threadIdx.x;
  int total = NB*NN*C;
  if (idx >= total) return;
  int c   = idx % C;
  int row = idx / C;
  int b = row >> 9;   // /NN
  int n = row & 511;
  float v;
  if (c == 0)       v = p0[b*bs0 + n];
  else if (c < ns)  v = p1[b*bs1 + n];
  else              v = hm[row*HH + (c - ns)];
  inp[row*CS + c] = v;
}

// ---------------- Y[b] = A[b] @ X[b]   (N x N) @ (N x C) ----------------
// grid (NN/64, NB), 256 threads. 64-row x 66-col tile; 16x16 threads x (4x4),
// extra 2 cols handled by first 128 threads.
__global__ __launch_bounds__(256) void graph_mm(
    const float* __restrict__ A, long long abstr,
    const float* __restrict__ X, float* __restrict__ Y, int C)
{
  __shared__ float At[64][68];   // [kk][row] transposed A tile
  __shared__ float Xs[64][68];   // [kk][col], zero-padded cols >= C
  int b = blockIdx.y;
  int row0 = blockIdx.x * 64;
  const float* Ab = A + (long long)b*abstr;
  const float* Xb = X + (long long)b*NN*CS;
  float* Yb = Y + (long long)b*NN*CS;
  int tid = threadIdx.x;
  int ty = tid >> 4, tx = tid & 15;
  float acc[4][4] = {};
  float acc_e = 0.f;
  int er = tid >> 1;          // rows 0..63 (for tid<128)
  int ec = 64 + (tid & 1);    // cols 64,65
  for (int mt = 0; mt < NN/64; ++mt) {
    int m0 = mt*64;
    #pragma unroll
    for (int i = 0; i < 16; ++i) {
      int lin = i*256 + tid;
      int kk = lin & 63;
      int r  = lin >> 6;
      At[kk][r] = Ab[(row0+r)*NN + m0 + kk];
    }
    #pragma unroll
    for (int i = 0; i < 17; ++i) {
      int lin = i*256 + tid;
      if (lin < 64*68) {
        int c  = lin % 68;
        int kk = lin / 68;
        Xs[kk][c] = (c < C) ? Xb[(m0+kk)*CS + c] : 0.f;
      }
    }
    __syncthreads();
    #pragma unroll 4
    for (int kk = 0; kk < 64; ++kk) {
      float4 a4 = *(const float4*)&At[kk][ty*4];
      float4 x4 = *(const float4*)&Xs[kk][tx*4];
      float a_[4] = {a4.x,a4.y,a4.z,a4.w};
      float x_[4] = {x4.x,x4.y,x4.z,x4.w};
      #pragma unroll
      for (int i = 0; i < 4; ++i)
        #pragma unroll
        for (int j = 0; j < 4; ++j)
          acc[i][j] += a_[i]*x_[j];
      if (tid < 128) acc_e += At[kk][er]*Xs[kk][ec];
    }
    __syncthreads();
  }
  #pragma unroll
  for (int i = 0; i < 4; ++i) {
    int row = row0 + ty*4 + i;
    #pragma unroll
    for (int j = 0; j < 4; ++j)
      Yb[row*CS + tx*4 + j] = acc[i][j];
  }
  if (tid < 128 && ec < C) Yb[(row0+er)*CS + ec] = acc_e;
}

// ---------------- gate dense: zr = sigmoid(inp*W0'+g1*W1'+g2*W2'+b) ----------------
// writes zh = z*h (cols 0..63) and r (cols 64..127). grid 256 blocks x 256 thr.
__global__ __launch_bounds__(256) void dense_gate(
    const float* __restrict__ inp, const float* __restrict__ g1, const float* __restrict__ g2,
    const float* __restrict__ W, const float* __restrict__ bias,
    const float* __restrict__ h, float* __restrict__ zh, float* __restrict__ rbuf, int C)
{
  __shared__ float Xs[66][68];   // [c][row]
  int row0 = blockIdx.x * 64;
  int tid = threadIdx.x;
  int ty = tid >> 4, tx = tid & 15;
  float acc[4][8] = {};
  #pragma unroll
  for (int s = 0; s < 3; ++s) {
    const float* Xp = (s==0) ? inp : (s==1) ? g1 : g2;
    #pragma unroll
    for (int i = 0; i < 17; ++i) {
      int lin = i*256 + tid;
      if (lin < 64*66) {
        int c = lin % 66;
        int r = lin / 66;
        if (c < C) Xs[c][r] = Xp[(row0+r)*CS + c];
      }
    }
    __syncthreads();
    const float* Wp = W + s*C*128;
    for (int c = 0; c < C; ++c) {
      float4 xv = *(const float4*)&Xs[c][ty*4];
      float4 w0 = *(const float4*)&Wp[c*128 + tx*8];
      float4 w1 = *(const float4*)&Wp[c*128 + tx*8 + 4];
      float x_[4] = {xv.x,xv.y,xv.z,xv.w};
      float w_[8] = {w0.x,w0.y,w0.z,w0.w,w1.x,w1.y,w1.z,w1.w};
      #pragma unroll
      for (int i = 0; i < 4; ++i)
        #pragma unroll
        for (int j = 0; j < 8; ++j)
          acc[i][j] += x_[i]*w_[j];
    }
    __syncthreads();
  }
  #pragma unroll
  for (int i = 0; i < 4; ++i) {
    int row = row0 + ty*4 + i;
    #pragma unroll
    for (int j = 0; j < 8; ++j) {
      int o = tx*8 + j;
      float v = sigmoidf_(acc[i][j] + bias[o]);
      if (o < HH) zh[row*HH + o] = v * h[row*HH + o];
      else        rbuf[row*HH + o - HH] = v;
    }
  }
}

// ---------------- update dense: hc = tanh(...); h = r*h + (1-r)*hc ----------------
__global__ __launch_bounds__(256) void dense_upd(
    const float* __restrict__ inp, const float* __restrict__ g1, const float* __restrict__ g2,
    const float* __restrict__ W, const float* __restrict__ bias,
    const float* __restrict__ rbuf, float* __restrict__ h, int C)
{
  __shared__ float Xs[66][68];
  int row0 = blockIdx.x * 64;
  int tid = threadIdx.x;
  int ty = tid >> 4, tx = tid & 15;
  float acc[4][4] = {};
  #pragma unroll
  for (int s = 0; s < 3; ++s) {
    const float* Xp = (s==0) ? inp : (s==1) ? g1 : g2;
    #pragma unroll
    for (int i = 0; i < 17; ++i) {
      int lin = i*256 + tid;
      if (lin < 64*66) {
        int c = lin % 66;
        int r = lin / 66;
        if (c < C) Xs[c][r] = Xp[(row0+r)*CS + c];
      }
    }
    __syncthreads();
    const float* Wp = W + s*C*64;
    for (int c = 0; c < C; ++c) {
      float4 xv = *(const float4*)&Xs[c][ty*4];
      float4 wv = *(const float4*)&Wp[c*64 + tx*4];
      float x_[4] = {xv.x,xv.y,xv.z,xv.w};
      float w_[4] = {wv.x,wv.y,wv.z,wv.w};
      #pragma unroll
      for (int i = 0; i < 4; ++i)
        #pragma unroll
        for (int j = 0; j < 4; ++j)
          acc[i][j] += x_[i]*w_[j];
    }
    __syncthreads();
  }
  #pragma unroll
  for (int i = 0; i < 4; ++i) {
    int row = row0 + ty*4 + i;
    #pragma unroll
    for (int j = 0; j < 4; ++j) {
      int o = tx*4 + j;
      float hc = tanhf(acc[i][j] + bias[o]);
      float rv = rbuf[row*HH + o];
      float hv = h[row*HH + o];
      h[row*HH + o] = rv*hv + (1.f - rv)*hc;
    }
  }
}

// ---------------- E_dyn = ne + h @ hyper_W + hyper_b ----------------
__global__ __launch_bounds__(256) void edyn_k(
    const float* __restrict__ h, const float* __restrict__ ne,
    const float* __restrict__ hW, const float* __restrict__ hb, float* __restrict__ Ed)
{
  int row = blockIdx.x*4 + (threadIdx.x >> 6);
  int lane = threadIdx.x & 63;
  float hv = h[row*HH + lane];
  float myval = 0.f;
  #pragma unroll
  for (int e = 0; e < EE; ++e) {
    float v = hv * hW[lane*EE + e];
    #pragma unroll
    for (int off = 32; off >= 1; off >>= 1) v += __shfl_xor(v, off, 64);
    if (lane == e) myval = v;
  }
  if (lane < EE) {
    int n = row & 511;
    Ed[row*EE + lane] = ne[n*EE + lane] + hb[lane] + myval;
  }
}

// ---------------- go = h @ proj_W + proj_b ; write output[:,t] ----------------
__global__ __launch_bounds__(256) void proj_k(
    const float* __restrict__ h, const float* __restrict__ pW, const float* __restrict__ pb,
    float* __restrict__ go, float* __restrict__ out, int t)
{
  int row = blockIdx.x*4 + (threadIdx.x >> 6);
  int lane = threadIdx.x & 63;
  float v = h[row*HH + lane] * pW[lane];
  #pragma unroll
  for (int off = 32; off >= 1; off >>= 1) v += __shfl_xor(v, off, 64);
  if (lane == 0) {
    float r = v + pb[0];
    go[row] = r;
    int b = row >> 9, n = row & 511;
    out[((long long)b*TT + t)*NN + n] = r;
  }
}

extern "C" void kernel_launch(void* const* d_in, const int* in_sizes, int n_in,
                              void* d_out, int out_size, void* d_ws, size_t ws_size,
                              hipStream_t stream)
{
  const float* x    = (const float*)d_in[0];
  const float* ycov = (const float*)d_in[1];
  const float* ne   = (const float*)d_in[2];
  const float* egW  = (const float*)d_in[3];
  const float* egb  = (const float*)d_in[4];
  const float* euW  = (const float*)d_in[5];
  const float* eub  = (const float*)d_in[6];
  const float* dgW  = (const float*)d_in[7];
  const float* dgb  = (const float*)d_in[8];
  const float* duW  = (const float*)d_in[9];
  const float* dub  = (const float*)d_in[10];
  const float* pW   = (const float*)d_in[11];
  const float* pb   = (const float*)d_in[12];
  const float* hW   = (const float*)d_in[13];
  const float* hb   = (const float*)d_in[14];
  float* out = (float*)d_out;
  float* ws  = (float*)d_ws;

  float* A_s = ws;
  float* A_d = A_s + 262144;          // NN*NN
  float* h   = A_d + 8388608;         // NB*NN*NN
  float* g1  = h   + 1048576;         // NB*NN*HH
  float* g2  = g1  + 1081344;         // NB*NN*CS
  float* inp = g2  + 1081344;
  float* zh  = inp + 1081344;
  float* rb  = zh  + 1048576;
  float* go  = rb  + 1048576;
  float* Ed  = go  + 16384;
  float* Wge = Ed  + 163840;
  float* Wue = Wge + 24960;           // 3*65*128
  float* Wgd = Wue + 12480;           // 3*65*64
  float* Wud = Wgd + 25344;           // 3*66*128

  fold_w<<<(3*65*128+255)/256, 256, 0, stream>>>(egW, Wge, 65, 128);
  fold_w<<<(3*65*64 +255)/256, 256, 0, stream>>>(euW, Wue, 65, 64);
  fold_w<<<(3*66*128+255)/256, 256, 0, stream>>>(dgW, Wgd, 66, 128);
  fold_w<<<(3*66*64 +255)/256, 256, 0, stream>>>(duW, Wud, 66, 64);

  softmax_graph<<<NN, 512, 0, stream>>>(ne, 0, A_s, 0);
  hipMemsetAsync(h, 0, (size_t)NB*NN*HH*sizeof(float), stream);

  for (int t = 0; t < TT; ++t) {
    const float* xt = x + (size_t)t*NN;
    build_inp<<<4160, 256, 0, stream>>>(xt, (long long)TT*NN, nullptr, 0, h, inp, 1, 65);
    graph_mm<<<dim3(8,NB), 256, 0, stream>>>(A_s, 0, inp, g1, 65);
    graph_mm<<<dim3(8,NB), 256, 0, stream>>>(A_s, 0, g1, g2, 65);
    dense_gate<<<256, 256, 0, stream>>>(inp, g1, g2, Wge, egb, h, zh, rb, 65);
    build_inp<<<4160, 256, 0, stream>>>(xt, (long long)TT*NN, nullptr, 0, zh, inp, 1, 65);
    graph_mm<<<dim3(8,NB), 256, 0, stream>>>(A_s, 0, inp, g1, 65);
    graph_mm<<<dim3(8,NB), 256, 0, stream>>>(A_s, 0, g1, g2, 65);
    dense_upd<<<256, 256, 0, stream>>>(inp, g1, g2, Wue, eub, rb, h, 65);
  }

  edyn_k<<<NB*NN/4, 256, 0, stream>>>(h, ne, hW, hb, Ed);
  softmax_graph<<<NB*NN, 512, 0, stream>>>(Ed, (long long)NN*EE, A_d, (long long)NN*NN);
  hipMemsetAsync(go, 0, (size_t)NB*NN*sizeof(float), stream);

  for (int t = 0; t < TT; ++t) {
    const float* yt = ycov + (size_t)t*NN;
    build_inp<<<4224, 256, 0, stream>>>(go, NN, yt, (long long)TT*NN, h, inp, 2, 66);
    graph_mm<<<dim3(8,NB), 256, 0, stream>>>(A_d, (long long)NN*NN, inp, g1, 66);
    graph_mm<<<dim3(8,NB), 256, 0, stream>>>(A_d, (long long)NN*NN, g1, g2, 66);
    dense_gate<<<256, 256, 0, stream>>>(inp, g1, g2, Wgd, dgb, h, zh, rb, 66);
    build_inp<<<4224, 256, 0, stream>>>(go, NN, yt, (long long)TT*NN, zh, inp, 2, 66);
    graph_mm<<<dim3(8,NB), 256, 0, stream>>>(A_d, (long long)NN*NN, inp, g1, 66);
    graph_mm<<<dim3(8,NB), 256, 0, stream>>>(A_d, (long long)NN*NN, g1, g2, 66);
    dense_upd<<<256, 256, 0, stream>>>(inp, g1, g2, Wud, dub, rb, h, 66);
    proj_k<<<NB*NN/4, 256, 0, stream>>>(h, pW, pb, go, out, t);
  }
}

// Round 3
// 3445.831 us; speedup vs baseline: 3.8307x; 3.8307x over previous
//
#include <hip/hip_runtime.h>

#define NB 32
#define TT 12
#define NN 512
#define HH 64
#define EE 10
#define CS 80      // padded feature stride (halves)
#define KD 240     // dense K = 3*CS

typedef _Float16 f16;
typedef __attribute__((ext_vector_type(4))) _Float16 f16x4;
typedef __attribute__((ext_vector_type(8))) _Float16 f16x8;
typedef __attribute__((ext_vector_type(4))) float f32x4;

__device__ __forceinline__ float sigmoidf_(float x){ return 1.f/(1.f+expf(-x)); }

// ---------------- fold Chebyshev into weights; transpose to [O][KD]; f16 split ----
// k = s*CS + c ; s=0: W0-W2 ; s=1: W1 ; s=2: 2*W2 ; c>=C -> 0
__global__ void fold_w_t(const float* __restrict__ src, f16* __restrict__ WtH,
                         f16* __restrict__ WtL, int C, int O){
  int idx = blockIdx.x*256 + threadIdx.x;
  if (idx >= O*KD) return;
  int o = idx / KD;
  int k = idx % KD;
  int s = k / CS, c = k % CS;
  float v = 0.f;
  if (c < C) {
    if (s == 0)      v = src[c*O+o] - src[(2*C+c)*O+o];
    else if (s == 1) v = src[(C+c)*O+o];
    else             v = 2.f*src[(2*C+c)*O+o];
  }
  f16 hi = (f16)v;
  WtH[idx] = hi;
  WtL[idx] = (f16)(v - (float)hi);
}

// ---------------- A = softmax(relu(E E^T)) per row, f16 split output -------------
__global__ __launch_bounds__(512) void softmax_graph(
    const float* __restrict__ Emb, long long ebs,
    f16* __restrict__ AH, f16* __restrict__ AL, long long abs_)
{
  __shared__ float Es[NN*EE];
  __shared__ float red[8];
  int gid = blockIdx.x;
  int b = gid / NN;
  int n = gid % NN;
  const float* Eb = Emb + (long long)b*ebs;
  int tid = threadIdx.x;
  for (int i = tid; i < NN*EE; i += 512) Es[i] = Eb[i];
  __syncthreads();
  float q[EE];
  #pragma unroll
  for (int e = 0; e < EE; ++e) q[e] = Es[n*EE+e];
  int m = tid;
  float s = 0.f;
  #pragma unroll
  for (int e = 0; e < EE; ++e) s += q[e]*Es[m*EE+e];
  s = fmaxf(s, 0.f);
  int lane = tid & 63, wave = tid >> 6;
  float mx = s;
  #pragma unroll
  for (int off = 32; off >= 1; off >>= 1) mx = fmaxf(mx, __shfl_xor(mx, off, 64));
  if (lane == 0) red[wave] = mx;
  __syncthreads();
  mx = red[0];
  #pragma unroll
  for (int w = 1; w < 8; ++w) mx = fmaxf(mx, red[w]);
  float ev = expf(s - mx);
  float sm = ev;
  #pragma unroll
  for (int off = 32; off >= 1; off >>= 1) sm += __shfl_xor(sm, off, 64);
  __syncthreads();
  if (lane == 0) red[wave] = sm;
  __syncthreads();
  float tot = 0.f;
  #pragma unroll
  for (int w = 0; w < 8; ++w) tot += red[w];
  float p = ev / tot;
  long long off_ = (long long)b*abs_ + (long long)n*NN + m;
  f16 hi = (f16)p;
  AH[off_] = hi;
  AL[off_] = (f16)(p - (float)hi);
}

// ---------------- build inp buffer (f16 split, padded to CS) ---------------------
__global__ void build_inp(const float* __restrict__ p0, long long bs0,
                          const float* __restrict__ p1, long long bs1,
                          const float* __restrict__ hm,
                          f16* __restrict__ XH, f16* __restrict__ XL, int ns)
{
  int idx = blockIdx.x*256 + threadIdx.x;
  if (idx >= NB*NN*CS) return;
  int c   = idx % CS;
  int row = idx / CS;
  int b = row >> 9;
  int n = row & 511;
  float v = 0.f;
  if (c == 0)            v = p0[b*bs0 + n];
  else if (c < ns)       v = p1[b*bs1 + n];
  else if (c < ns + HH)  v = hm[row*HH + (c - ns)];
  f16 hi = (f16)v;
  XH[idx] = hi;
  XL[idx] = (f16)(v - (float)hi);
}

// ---------------- Y[b] = A[b] @ X[b] via 16x16x32 f16 MFMA, split operands -------
// grid (NN/64, NB), 256 threads (4 waves); tile 64 rows x 80 cols.
__global__ __launch_bounds__(256) void graph_mm_f16(
    const f16* __restrict__ AH, const f16* __restrict__ AL, long long astr,
    const f16* __restrict__ XH, const f16* __restrict__ XL,
    f16* __restrict__ YH, f16* __restrict__ YL)
{
  __shared__ f16 AsH[64][32], AsL[64][32], XtH[80][32], XtL[80][32];
  int b = blockIdx.y;
  int rows0 = blockIdx.x * 64;
  const f16* Ah = AH + (long long)b*astr;
  const f16* Al = AL + (long long)b*astr;
  const f16* Xh = XH + (long long)b*NN*CS;
  const f16* Xl = XL + (long long)b*NN*CS;
  int tid = threadIdx.x;
  int l = tid & 63, w = tid >> 6;
  int lr = l & 15, lg = l >> 4;
  int ar  = w*16 + lr;
  int asw = (ar >> 2) & 3;
  int st_row = tid >> 2, st_seg = tid & 3;   // A staging: 64 rows x 4 segs of 8
  int sx_m = tid >> 3, sx_sub = tid & 7;     // X staging: 32 m x chunks of 4 cols
  f32x4 acc[5] = {};
  for (int kt = 0; kt < 16; ++kt) {
    int k0 = kt*32;
    __syncthreads();
    {
      f16x8 vh = *(const f16x8*)&Ah[(long long)(rows0+st_row)*NN + k0 + 8*st_seg];
      f16x8 vl = *(const f16x8*)&Al[(long long)(rows0+st_row)*NN + k0 + 8*st_seg];
      int sw = (st_row >> 2) & 3;
      *(f16x8*)&AsH[st_row][8*(st_seg ^ sw)] = vh;
      *(f16x8*)&AsL[st_row][8*(st_seg ^ sw)] = vl;
    }
    for (int c4 = sx_sub; c4 < 20; c4 += 8) {
      f16x4 vh = *(const f16x4*)&Xh[(long long)(k0 + sx_m)*CS + 4*c4];
      f16x4 vl = *(const f16x4*)&Xl[(long long)(k0 + sx_m)*CS + 4*c4];
      int mm = sx_m ^ (8*(c4 & 3));
      for (int j = 0; j < 4; ++j) {
        XtH[4*c4 + j][mm] = vh[j];
        XtL[4*c4 + j][mm] = vl[j];
      }
    }
    __syncthreads();
    f16x8 a_h = *(const f16x8*)&AsH[ar][8*(lg ^ asw)];
    f16x8 a_l = *(const f16x8*)&AsL[ar][8*(lg ^ asw)];
    #pragma unroll
    for (int cf = 0; cf < 5; ++cf) {
      int c = cf*16 + lr;
      int xs = (c >> 2) & 3;
      f16x8 b_h = *(const f16x8*)&XtH[c][8*(lg ^ xs)];
      f16x8 b_l = *(const f16x8*)&XtL[c][8*(lg ^ xs)];
      acc[cf] = __builtin_amdgcn_mfma_f32_16x16x32_f16(a_h, b_h, acc[cf], 0,0,0);
      acc[cf] = __builtin_amdgcn_mfma_f32_16x16x32_f16(a_h, b_l, acc[cf], 0,0,0);
      acc[cf] = __builtin_amdgcn_mfma_f32_16x16x32_f16(a_l, b_h, acc[cf], 0,0,0);
    }
  }
  #pragma unroll
  for (int cf = 0; cf < 5; ++cf) {
    int col = cf*16 + lr;
    #pragma unroll
    for (int reg = 0; reg < 4; ++reg) {
      int rg = rows0 + w*16 + lg*4 + reg;
      float v = acc[cf][reg];
      f16 hi = (f16)v;
      long long o = ((long long)b*NN + rg)*CS + col;
      YH[o] = hi;
      YL[o] = (f16)(v - (float)hi);
    }
  }
}

// ---------------- dense gate: zr = sigmoid(X*W'+b); zh = z*h; rb = r -------------
// X = [inp|g1|g2] splits as A-operand (direct global), W staged in LDS.
__global__ __launch_bounds__(256) void dense_gate_f16(
    const f16* __restrict__ inpH, const f16* __restrict__ inpL,
    const f16* __restrict__ g1H,  const f16* __restrict__ g1L,
    const f16* __restrict__ g2H,  const f16* __restrict__ g2L,
    const f16* __restrict__ WtH,  const f16* __restrict__ WtL,
    const float* __restrict__ bias, const float* __restrict__ h,
    float* __restrict__ zh, float* __restrict__ rb)
{
  __shared__ f16 WsH[128][24], WsL[128][24];
  int rows0 = blockIdx.x * 64;
  int tid = threadIdx.x;
  int l = tid & 63, w = tid >> 6;
  int lr = l & 15, lg = l >> 4;
  int arow = rows0 + w*16 + lr;
  f32x4 acc[8] = {};
  const f16* XHs[3] = {inpH, g1H, g2H};
  const f16* XLs[3] = {inpL, g1L, g2L};
  for (int s = 0; s < 3; ++s) {
    const f16* rowH = XHs[s] + (long long)arow*CS;
    const f16* rowL = XLs[s] + (long long)arow*CS;
    for (int ks = 0; ks < 5; ++ks) {
      int k0g = s*CS + ks*16;
      __syncthreads();
      {
        int o = tid >> 1, part = tid & 1;
        *(f16x8*)&WsH[o][8*part] = *(const f16x8*)&WtH[o*KD + k0g + 8*part];
        *(f16x8*)&WsL[o][8*part] = *(const f16x8*)&WtL[o*KD + k0g + 8*part];
      }
      __syncthreads();
      f16x4 a_h = *(const f16x4*)&rowH[ks*16 + 4*lg];
      f16x4 a_l = *(const f16x4*)&rowL[ks*16 + 4*lg];
      #pragma unroll
      for (int cf = 0; cf < 8; ++cf) {
        f16x4 b_h = *(const f16x4*)&WsH[cf*16 + lr][4*lg];
        f16x4 b_l = *(const f16x4*)&WsL[cf*16 + lr][4*lg];
        acc[cf] = __builtin_amdgcn_mfma_f32_16x16x16f16(a_h, b_h, acc[cf], 0,0,0);
        acc[cf] = __builtin_amdgcn_mfma_f32_16x16x16f16(a_h, b_l, acc[cf], 0,0,0);
        acc[cf] = __builtin_amdgcn_mfma_f32_16x16x16f16(a_l, b_h, acc[cf], 0,0,0);
      }
    }
  }
  #pragma unroll
  for (int cf = 0; cf < 8; ++cf) {
    int o = cf*16 + lr;
    float bi = bias[o];
    #pragma unroll
    for (int reg = 0; reg < 4; ++reg) {
      int rg = rows0 + w*16 + lg*4 + reg;
      float v = sigmoidf_(acc[cf][reg] + bi);
      if (o < HH) zh[rg*HH + o] = v * h[rg*HH + o];
      else        rb[rg*HH + o - HH] = v;
    }
  }
}

// ---------------- dense update: hc = tanh(X*W'+b); h = r*h + (1-r)*hc ------------
__global__ __launch_bounds__(256) void dense_upd_f16(
    const f16* __restrict__ inpH, const f16* __restrict__ inpL,
    const f16* __restrict__ g1H,  const f16* __restrict__ g1L,
    const f16* __restrict__ g2H,  const f16* __restrict__ g2L,
    const f16* __restrict__ WtH,  const f16* __restrict__ WtL,
    const float* __restrict__ bias, const float* __restrict__ rb,
    float* __restrict__ h)
{
  __shared__ f16 WsH[64][24], WsL[64][24];
  int rows0 = blockIdx.x * 64;
  int tid = threadIdx.x;
  int l = tid & 63, w = tid >> 6;
  int lr = l & 15, lg = l >> 4;
  int arow = rows0 + w*16 + lr;
  f32x4 acc[4] = {};
  const f16* XHs[3] = {inpH, g1H, g2H};
  const f16* XLs[3] = {inpL, g1L, g2L};
  for (int s = 0; s < 3; ++s) {
    const f16* rowH = XHs[s] + (long long)arow*CS;
    const f16* rowL = XLs[s] + (long long)arow*CS;
    for (int ks = 0; ks < 5; ++ks) {
      int k0g = s*CS + ks*16;
      __syncthreads();
      if (tid < 128) {
        int o = tid >> 1, part = tid & 1;
        *(f16x8*)&WsH[o][8*part] = *(const f16x8*)&WtH[o*KD + k0g + 8*part];
        *(f16x8*)&WsL[o][8*part] = *(const f16x8*)&WtL[o*KD + k0g + 8*part];
      }
      __syncthreads();
      f16x4 a_h = *(const f16x4*)&rowH[ks*16 + 4*lg];
      f16x4 a_l = *(const f16x4*)&rowL[ks*16 + 4*lg];
      #pragma unroll
      for (int cf = 0; cf < 4; ++cf) {
        f16x4 b_h = *(const f16x4*)&WsH[cf*16 + lr][4*lg];
        f16x4 b_l = *(const f16x4*)&WsL[cf*16 + lr][4*lg];
        acc[cf] = __builtin_amdgcn_mfma_f32_16x16x16f16(a_h, b_h, acc[cf], 0,0,0);
        acc[cf] = __builtin_amdgcn_mfma_f32_16x16x16f16(a_h, b_l, acc[cf], 0,0,0);
        acc[cf] = __builtin_amdgcn_mfma_f32_16x16x16f16(a_l, b_h, acc[cf], 0,0,0);
      }
    }
  }
  #pragma unroll
  for (int cf = 0; cf < 4; ++cf) {
    int o = cf*16 + lr;
    float bi = bias[o];
    #pragma unroll
    for (int reg = 0; reg < 4; ++reg) {
      int rg = rows0 + w*16 + lg*4 + reg;
      float hc = tanhf(acc[cf][reg] + bi);
      float rv = rb[rg*HH + o];
      float hv = h[rg*HH + o];
      h[rg*HH + o] = rv*hv + (1.f - rv)*hc;
    }
  }
}

// ---------------- E_dyn = ne + h @ hyper_W + hyper_b -----------------------------
__global__ __launch_bounds__(256) void edyn_k(
    const float* __restrict__ h, const float* __restrict__ ne,
    const float* __restrict__ hW, const float* __restrict__ hb, float* __restrict__ Ed)
{
  int row = blockIdx.x*4 + (threadIdx.x >> 6);
  int lane = threadIdx.x & 63;
  float hv = h[row*HH + lane];
  float myval = 0.f;
  #pragma unroll
  for (int e = 0; e < EE; ++e) {
    float v = hv * hW[lane*EE + e];
    #pragma unroll
    for (int off = 32; off >= 1; off >>= 1) v += __shfl_xor(v, off, 64);
    if (lane == e) myval = v;
  }
  if (lane < EE) {
    int n = row & 511;
    Ed[row*EE + lane] = ne[n*EE + lane] + hb[lane] + myval;
  }
}

// ---------------- go = h @ proj_W + proj_b ; write output[:,t] -------------------
__global__ __launch_bounds__(256) void proj_k(
    const float* __restrict__ h, const float* __restrict__ pW, const float* __restrict__ pb,
    float* __restrict__ go, float* __restrict__ out, int t)
{
  int row = blockIdx.x*4 + (threadIdx.x >> 6);
  int lane = threadIdx.x & 63;
  float v = h[row*HH + lane] * pW[lane];
  #pragma unroll
  for (int off = 32; off >= 1; off >>= 1) v += __shfl_xor(v, off, 64);
  if (lane == 0) {
    float r = v + pb[0];
    go[row] = r;
    int b = row >> 9, n = row & 511;
    out[((long long)b*TT + t)*NN + n] = r;
  }
}

extern "C" void kernel_launch(void* const* d_in, const int* in_sizes, int n_in,
                              void* d_out, int out_size, void* d_ws, size_t ws_size,
                              hipStream_t stream)
{
  const float* x    = (const float*)d_in[0];
  const float* ycov = (const float*)d_in[1];
  const float* ne   = (const float*)d_in[2];
  const float* egW  = (const float*)d_in[3];
  const float* egb  = (const float*)d_in[4];
  const float* euW  = (const float*)d_in[5];
  const float* eub  = (const float*)d_in[6];
  const float* dgW  = (const float*)d_in[7];
  const float* dgb  = (const float*)d_in[8];
  const float* duW  = (const float*)d_in[9];
  const float* dub  = (const float*)d_in[10];
  const float* pW   = (const float*)d_in[11];
  const float* pb   = (const float*)d_in[12];
  const float* hW   = (const float*)d_in[13];
  const float* hb   = (const float*)d_in[14];
  float* out = (float*)d_out;

  char* p = (char*)d_ws;
  f16* AsH = (f16*)p; p += (size_t)NN*NN*2;
  f16* AsL = (f16*)p; p += (size_t)NN*NN*2;
  f16* AdH = (f16*)p; p += (size_t)NB*NN*NN*2;
  f16* AdL = (f16*)p; p += (size_t)NB*NN*NN*2;
  f16* inpH = (f16*)p; p += (size_t)NB*NN*CS*2;
  f16* inpL = (f16*)p; p += (size_t)NB*NN*CS*2;
  f16* g1H  = (f16*)p; p += (size_t)NB*NN*CS*2;
  f16* g1L  = (f16*)p; p += (size_t)NB*NN*CS*2;
  f16* g2H  = (f16*)p; p += (size_t)NB*NN*CS*2;
  f16* g2L  = (f16*)p; p += (size_t)NB*NN*CS*2;
  float* h  = (float*)p; p += (size_t)NB*NN*HH*4;
  float* zh = (float*)p; p += (size_t)NB*NN*HH*4;   // also aliased as Ed (dead then)
  float* rb = (float*)p; p += (size_t)NB*NN*HH*4;
  float* go = (float*)p; p += (size_t)NB*NN*4;
  f16* WgeH = (f16*)p; p += (size_t)128*KD*2;
  f16* WgeL = (f16*)p; p += (size_t)128*KD*2;
  f16* WueH = (f16*)p; p += (size_t)64*KD*2;
  f16* WueL = (f16*)p; p += (size_t)64*KD*2;
  f16* WgdH = (f16*)p; p += (size_t)128*KD*2;
  f16* WgdL = (f16*)p; p += (size_t)128*KD*2;
  f16* WudH = (f16*)p; p += (size_t)64*KD*2;
  f16* WudL = (f16*)p; p += (size_t)64*KD*2;
  float* Ed = zh;  // alias: zh is dead between last encoder step and first decoder gate

  fold_w_t<<<(128*KD+255)/256, 256, 0, stream>>>(egW, WgeH, WgeL, 65, 128);
  fold_w_t<<<(64*KD +255)/256, 256, 0, stream>>>(euW, WueH, WueL, 65, 64);
  fold_w_t<<<(128*KD+255)/256, 256, 0, stream>>>(dgW, WgdH, WgdL, 66, 128);
  fold_w_t<<<(64*KD +255)/256, 256, 0, stream>>>(duW, WudH, WudL, 66, 64);

  softmax_graph<<<NN, 512, 0, stream>>>(ne, 0, AsH, AsL, 0);
  (void)hipMemsetAsync(h, 0, (size_t)NB*NN*HH*4, stream);

  for (int t = 0; t < TT; ++t) {
    const float* xt = x + (size_t)t*NN;
    build_inp<<<(NB*NN*CS+255)/256, 256, 0, stream>>>(xt, (long long)TT*NN, nullptr, 0, h, inpH, inpL, 1);
    graph_mm_f16<<<dim3(8,NB), 256, 0, stream>>>(AsH, AsL, 0, inpH, inpL, g1H, g1L);
    graph_mm_f16<<<dim3(8,NB), 256, 0, stream>>>(AsH, AsL, 0, g1H, g1L, g2H, g2L);
    dense_gate_f16<<<256, 256, 0, stream>>>(inpH, inpL, g1H, g1L, g2H, g2L, WgeH, WgeL, egb, h, zh, rb);
    build_inp<<<(NB*NN*CS+255)/256, 256, 0, stream>>>(xt, (long long)TT*NN, nullptr, 0, zh, inpH, inpL, 1);
    graph_mm_f16<<<dim3(8,NB), 256, 0, stream>>>(AsH, AsL, 0, inpH, inpL, g1H, g1L);
    graph_mm_f16<<<dim3(8,NB), 256, 0, stream>>>(AsH, AsL, 0, g1H, g1L, g2H, g2L);
    dense_upd_f16<<<256, 256, 0, stream>>>(inpH, inpL, g1H, g1L, g2H, g2L, WueH, WueL, eub, rb, h);
  }

  edyn_k<<<NB*NN/4, 256, 0, stream>>>(h, ne, hW, hb, Ed);
  softmax_graph<<<NB*NN, 512, 0, stream>>>(Ed, (long long)NN*EE, AdH, AdL, (long long)NN*NN);
  (void)hipMemsetAsync(go, 0, (size_t)NB*NN*4, stream);

  for (int t = 0; t < TT; ++t) {
    const float* yt = ycov + (size_t)t*NN;
    build_inp<<<(NB*NN*CS+255)/256, 256, 0, stream>>>(go, NN, yt, (long long)TT*NN, h, inpH, inpL, 2);
    graph_mm_f16<<<dim3(8,NB), 256, 0, stream>>>(AdH, AdL, (long long)NN*NN, inpH, inpL, g1H, g1L);
    graph_mm_f16<<<dim3(8,NB), 256, 0, stream>>>(AdH, AdL, (long long)NN*NN, g1H, g1L, g2H, g2L);
    dense_gate_f16<<<256, 256, 0, stream>>>(inpH, inpL, g1H, g1L, g2H, g2L, WgdH, WgdL, dgb, h, zh, rb);
    build_inp<<<(NB*NN*CS+255)/256, 256, 0, stream>>>(go, NN, yt, (long long)TT*NN, zh, inpH, inpL, 2);
    graph_mm_f16<<<dim3(8,NB), 256, 0, stream>>>(AdH, AdL, (long long)NN*NN, inpH, inpL, g1H, g1L);
    graph_mm_f16<<<dim3(8,NB), 256, 0, stream>>>(AdH, AdL, (long long)NN*NN, g1H, g1L, g2H, g2L);
    dense_upd_f16<<<256, 256, 0, stream>>>(inpH, inpL, g1H, g1L, g2H, g2L, WudH, WudL, dub, rb, h);
    proj_k<<<NB*NN/4, 256, 0, stream>>>(h, pW, pb, go, out, t);
  }
}

// Round 4
// 2117.167 us; speedup vs baseline: 6.2347x; 1.6276x over previous
//
#include <hip/hip_runtime.h>

#define NB 32
#define TT 12
#define NN 512
#define HH 64
#define EE 10
#define CSUB 80     // per-stage feature sub-block (halves)
#define KD 240      // unified X row length = 3*CSUB
#define TTNN (TT*NN)

typedef _Float16 f16;
typedef __attribute__((ext_vector_type(4))) _Float16 f16x4;
typedef __attribute__((ext_vector_type(8))) _Float16 f16x8;
typedef __attribute__((ext_vector_type(4))) float f32x4;

// ---------------- fold Chebyshev into weights; transpose to [O][KD]; f16 split ----
__global__ void fold_w_t(const float* __restrict__ src, f16* __restrict__ WtH,
                         f16* __restrict__ WtL, int C, int O){
  int idx = blockIdx.x*256 + threadIdx.x;
  if (idx >= O*KD) return;
  int o = idx / KD;
  int k = idx % KD;
  int s = k / CSUB, c = k % CSUB;
  float v = 0.f;
  if (c < C) {
    if (s == 0)      v = src[c*O+o] - src[(2*C+c)*O+o];
    else if (s == 1) v = src[(C+c)*O+o];
    else             v = 2.f*src[(2*C+c)*O+o];
  }
  f16 hi = (f16)v;
  WtH[idx] = hi;
  WtL[idx] = (f16)(v - (float)hi);
}

// ---------------- A = softmax(relu(E E^T)): 8 rows/block, wave-per-row ----------
__global__ __launch_bounds__(512) void softmax_graph(
    const float* __restrict__ Emb, long long ebs,
    f16* __restrict__ AH, f16* __restrict__ AL, long long abs_)
{
  __shared__ float Es[NN*EE];
  int b  = blockIdx.x >> 6;
  int rt = blockIdx.x & 63;
  const float* Eb = Emb + (long long)b*ebs;
  int tid = threadIdx.x;
  for (int i = tid; i < NN*EE; i += 512) Es[i] = Eb[i];
  __syncthreads();
  int wave = tid >> 6, lane = tid & 63;
  int r = rt*8 + wave;
  float q[EE];
  #pragma unroll
  for (int e = 0; e < EE; ++e) q[e] = Es[r*EE + e];
  float sv[8];
  float mx = 0.f;
  #pragma unroll
  for (int j = 0; j < 8; ++j) {
    int m = 64*j + lane;
    float s = 0.f;
    #pragma unroll
    for (int e = 0; e < EE; ++e) s += q[e]*Es[m*EE + e];
    s = fmaxf(s, 0.f);
    sv[j] = s;
    mx = fmaxf(mx, s);
  }
  #pragma unroll
  for (int off = 32; off >= 1; off >>= 1) mx = fmaxf(mx, __shfl_xor(mx, off, 64));
  float sm = 0.f;
  #pragma unroll
  for (int j = 0; j < 8; ++j) { sv[j] = expf(sv[j] - mx); sm += sv[j]; }
  #pragma unroll
  for (int off = 32; off >= 1; off >>= 1) sm += __shfl_xor(sm, off, 64);
  float inv = 1.f / sm;
  #pragma unroll
  for (int j = 0; j < 8; ++j) {
    int m = 64*j + lane;
    float p = sv[j] * inv;
    long long o = (long long)b*abs_ + (long long)r*NN + m;
    f16 hi = (f16)p;
    AH[o] = hi;
    AL[o] = (f16)(p - (float)hi);
  }
}

// ---------------- write one special column of X (split) -------------------------
__global__ void fill_col(f16* __restrict__ XH, f16* __restrict__ XL, int col,
                         const float* __restrict__ src, long long sstr){
  int row = blockIdx.x*256 + threadIdx.x;
  if (row >= NB*NN) return;
  float v = src[(long long)(row>>9)*sstr + (row & 511)];
  f16 hi = (f16)v;
  XH[(long long)row*KD + col] = hi;
  XL[(long long)row*KD + col] = (f16)(v - (float)hi);
}

// ---------------- X[:, src+80:src+160] = A @ X[:, src:src+80] -------------------
// grid (NB, 8) — batch-major so one batch's 8 row-tiles co-locate on one XCD.
// 256 thr / 4 waves; dbuf LDS + 2-deep reg prefetch, 1 barrier per K-iter.
__global__ __launch_bounds__(256) void graph_mm_f16(
    const f16* __restrict__ AH, const f16* __restrict__ AL, long long astr,
    f16* __restrict__ XH, f16* __restrict__ XL, int src_off)
{
  __shared__ f16 AsH[2][64][32], AsL[2][64][32], XtH[2][80][32], XtL[2][80][32];
  int b = blockIdx.x;
  int rows0 = blockIdx.y * 64;
  const f16* Ah = AH + (long long)b*astr;
  const f16* Al = AL + (long long)b*astr;
  f16* Xh = XH + (long long)b*NN*KD;
  f16* Xl = XL + (long long)b*NN*KD;
  int tid = threadIdx.x;
  int l = tid & 63, w = tid >> 6;
  int lr = l & 15, lg = l >> 4;
  int ar = w*16 + lr;
  int asw = (ar >> 2) & 3;
  int st_row = tid >> 2, st_seg = tid & 3;   // A staging: 64 rows x 4 segs of 8
  int sx_m = tid >> 3, sx_sub = tid & 7;     // X staging: 32 k x col-chunks of 4
  int a_sw = (st_row >> 2) & 3;

  f16x8 a0H, a0L, a1H, a1L;
  f16x4 x0H[3], x0L[3], x1H[3], x1L[3];

  auto LOAD = [&](int kt, f16x8& aH, f16x8& aL, f16x4* xH, f16x4* xL){
    int k0 = kt*32;
    aH = *(const f16x8*)&Ah[(long long)(rows0+st_row)*NN + k0 + 8*st_seg];
    aL = *(const f16x8*)&Al[(long long)(rows0+st_row)*NN + k0 + 8*st_seg];
    #pragma unroll
    for (int j = 0; j < 3; ++j) {
      int c4 = sx_sub + 8*j;
      if (c4 < 20) {
        xH[j] = *(const f16x4*)&Xh[(long long)(k0+sx_m)*KD + src_off + 4*c4];
        xL[j] = *(const f16x4*)&Xl[(long long)(k0+sx_m)*KD + src_off + 4*c4];
      }
    }
  };
  auto STORE = [&](int buf, f16x8& aH, f16x8& aL, f16x4* xH, f16x4* xL){
    *(f16x8*)&AsH[buf][st_row][8*(st_seg ^ a_sw)] = aH;
    *(f16x8*)&AsL[buf][st_row][8*(st_seg ^ a_sw)] = aL;
    #pragma unroll
    for (int j = 0; j < 3; ++j) {
      int c4 = sx_sub + 8*j;
      if (c4 < 20) {
        int mm = sx_m ^ (8*(c4 & 3));
        #pragma unroll
        for (int q = 0; q < 4; ++q) {
          XtH[buf][4*c4+q][mm] = xH[j][q];
          XtL[buf][4*c4+q][mm] = xL[j][q];
        }
      }
    }
  };
  f32x4 acc[5] = {};
  auto COMP = [&](int buf){
    f16x8 a_h = *(const f16x8*)&AsH[buf][ar][8*(lg ^ asw)];
    f16x8 a_l = *(const f16x8*)&AsL[buf][ar][8*(lg ^ asw)];
    #pragma unroll
    for (int cf = 0; cf < 5; ++cf) {
      int c = cf*16 + lr;
      int xs = (c >> 2) & 3;
      f16x8 b_h = *(const f16x8*)&XtH[buf][c][8*(lg ^ xs)];
      f16x8 b_l = *(const f16x8*)&XtL[buf][c][8*(lg ^ xs)];
      acc[cf] = __builtin_amdgcn_mfma_f32_16x16x32_f16(a_h, b_h, acc[cf], 0,0,0);
      acc[cf] = __builtin_amdgcn_mfma_f32_16x16x32_f16(a_h, b_l, acc[cf], 0,0,0);
      acc[cf] = __builtin_amdgcn_mfma_f32_16x16x32_f16(a_l, b_h, acc[cf], 0,0,0);
    }
  };

  LOAD(0, a0H,a0L,x0H,x0L);
  LOAD(1, a1H,a1L,x1H,x1L);
  STORE(0, a0H,a0L,x0H,x0L);
  __syncthreads();
  for (int kt2 = 0; kt2 < 8; ++kt2) {
    int kt = kt2*2;
    if (kt+2 < 16) LOAD(kt+2, a0H,a0L,x0H,x0L);
    COMP(0);
    STORE(1, a1H,a1L,x1H,x1L);
    __syncthreads();
    if (kt+3 < 16) LOAD(kt+3, a1H,a1L,x1H,x1L);
    COMP(1);
    if (kt+2 < 16) STORE(0, a0H,a0L,x0H,x0L);
    __syncthreads();
  }
  int dst = src_off + 80;
  #pragma unroll
  for (int cf = 0; cf < 5; ++cf) {
    int col = cf*16 + lr;
    #pragma unroll
    for (int reg = 0; reg < 4; ++reg) {
      int rg = rows0 + w*16 + lg*4 + reg;
      float v = acc[cf][reg];
      f16 hi = (f16)v;
      Xh[(long long)rg*KD + dst + col] = hi;
      Xl[(long long)rg*KD + dst + col] = (f16)(v - (float)hi);
    }
  }
}

// ---------------- gate: zr = sigmoid(X @ W' + b); writes X2 in place -------------
__global__ __launch_bounds__(256) void dense_gate_f16(
    f16* __restrict__ XH, f16* __restrict__ XL,
    const f16* __restrict__ WtH, const f16* __restrict__ WtL,
    const float* __restrict__ bias, const float* __restrict__ h,
    float* __restrict__ rb,
    const float* __restrict__ p0, long long p0s,
    const float* __restrict__ p1, long long p1s, int ns)
{
  __shared__ f16 WsH[128][84], WsL[128][84];
  int rows0 = blockIdx.x * 64;
  int tid = threadIdx.x;
  int l = tid & 63, w = tid >> 6;
  int lr = l & 15, lg = l >> 4;
  long long arow = rows0 + w*16 + lr;
  const f16* rowH = XH + arow*KD;
  const f16* rowL = XL + arow*KD;
  int so = tid >> 1, sp = tid & 1;
  f32x4 acc[8] = {};
  for (int s = 0; s < 3; ++s) {
    __syncthreads();
    #pragma unroll
    for (int ch = 0; ch < 5; ++ch) {
      int c8 = 2*ch + sp;
      *(f16x8*)&WsH[so][8*c8] = *(const f16x8*)&WtH[(long long)so*KD + s*80 + 8*c8];
      *(f16x8*)&WsL[so][8*c8] = *(const f16x8*)&WtL[(long long)so*KD + s*80 + 8*c8];
    }
    __syncthreads();
    #pragma unroll
    for (int ks = 0; ks < 5; ++ks) {
      f16x4 a_h = *(const f16x4*)&rowH[s*80 + ks*16 + 4*lg];
      f16x4 a_l = *(const f16x4*)&rowL[s*80 + ks*16 + 4*lg];
      #pragma unroll
      for (int cf = 0; cf < 8; ++cf) {
        f16x4 b_h = *(const f16x4*)&WsH[cf*16 + lr][ks*16 + 4*lg];
        f16x4 b_l = *(const f16x4*)&WsL[cf*16 + lr][ks*16 + 4*lg];
        acc[cf] = __builtin_amdgcn_mfma_f32_16x16x16f16(a_h, b_h, acc[cf], 0,0,0);
        acc[cf] = __builtin_amdgcn_mfma_f32_16x16x16f16(a_h, b_l, acc[cf], 0,0,0);
        acc[cf] = __builtin_amdgcn_mfma_f32_16x16x16f16(a_l, b_h, acc[cf], 0,0,0);
      }
    }
  }
  __syncthreads();   // all X reads done before in-place writes
  #pragma unroll
  for (int cf = 0; cf < 8; ++cf) {
    int o = cf*16 + lr;
    float bi = bias[o];
    #pragma unroll
    for (int reg = 0; reg < 4; ++reg) {
      int rg = rows0 + w*16 + lg*4 + reg;
      float v = 1.f/(1.f + expf(-(acc[cf][reg] + bi)));
      if (o < HH) {
        float zh = v * h[(long long)rg*HH + o];
        f16 hi = (f16)zh;
        XH[(long long)rg*KD + ns + o] = hi;
        XL[(long long)rg*KD + ns + o] = (f16)(zh - (float)hi);
      } else {
        rb[(long long)rg*HH + o - HH] = v;
      }
    }
  }
  if (lr == 0) {
    #pragma unroll
    for (int reg = 0; reg < 4; ++reg) {
      int rg = rows0 + w*16 + lg*4 + reg;
      int bb = rg >> 9, n = rg & 511;
      float v0 = p0[(long long)bb*p0s + n];
      f16 h0 = (f16)v0;
      XH[(long long)rg*KD] = h0;
      XL[(long long)rg*KD] = (f16)(v0 - (float)h0);
      if (ns > 1) {
        float v1 = p1[(long long)bb*p1s + n];
        f16 h1 = (f16)v1;
        XH[(long long)rg*KD + 1] = h1;
        XL[(long long)rg*KD + 1] = (f16)(v1 - (float)h1);
      }
    }
  }
}

// ---------------- update: h = r*h + (1-r)*tanh(X@W'+b); writes next X1 ----------
__global__ __launch_bounds__(256) void dense_upd_f16(
    f16* __restrict__ XH, f16* __restrict__ XL,
    const f16* __restrict__ WtH, const f16* __restrict__ WtL,
    const float* __restrict__ bias, const float* __restrict__ rb,
    float* __restrict__ h, int ns_next, int zero0,
    const float* __restrict__ p0, long long p0s,
    const float* __restrict__ p1, long long p1s)
{
  __shared__ f16 WsH[64][84], WsL[64][84];
  int rows0 = blockIdx.x * 64;
  int tid = threadIdx.x;
  int l = tid & 63, w = tid >> 6;
  int lr = l & 15, lg = l >> 4;
  long long arow = rows0 + w*16 + lr;
  const f16* rowH = XH + arow*KD;
  const f16* rowL = XL + arow*KD;
  f32x4 acc[4] = {};
  for (int s = 0; s < 3; ++s) {
    __syncthreads();
    if (tid < 128) {
      int so = tid >> 1, sp = tid & 1;
      #pragma unroll
      for (int ch = 0; ch < 5; ++ch) {
        int c8 = 2*ch + sp;
        *(f16x8*)&WsH[so][8*c8] = *(const f16x8*)&WtH[(long long)so*KD + s*80 + 8*c8];
        *(f16x8*)&WsL[so][8*c8] = *(const f16x8*)&WtL[(long long)so*KD + s*80 + 8*c8];
      }
    }
    __syncthreads();
    #pragma unroll
    for (int ks = 0; ks < 5; ++ks) {
      f16x4 a_h = *(const f16x4*)&rowH[s*80 + ks*16 + 4*lg];
      f16x4 a_l = *(const f16x4*)&rowL[s*80 + ks*16 + 4*lg];
      #pragma unroll
      for (int cf = 0; cf < 4; ++cf) {
        f16x4 b_h = *(const f16x4*)&WsH[cf*16 + lr][ks*16 + 4*lg];
        f16x4 b_l = *(const f16x4*)&WsL[cf*16 + lr][ks*16 + 4*lg];
        acc[cf] = __builtin_amdgcn_mfma_f32_16x16x16f16(a_h, b_h, acc[cf], 0,0,0);
        acc[cf] = __builtin_amdgcn_mfma_f32_16x16x16f16(a_h, b_l, acc[cf], 0,0,0);
        acc[cf] = __builtin_amdgcn_mfma_f32_16x16x16f16(a_l, b_h, acc[cf], 0,0,0);
      }
    }
  }
  __syncthreads();
  #pragma unroll
  for (int cf = 0; cf < 4; ++cf) {
    int o = cf*16 + lr;
    float bi = bias[o];
    #pragma unroll
    for (int reg = 0; reg < 4; ++reg) {
      int rg = rows0 + w*16 + lg*4 + reg;
      float hc = tanhf(acc[cf][reg] + bi);
      float rv = rb[(long long)rg*HH + o];
      float hv = h[(long long)rg*HH + o];
      float hn = rv*hv + (1.f - rv)*hc;
      h[(long long)rg*HH + o] = hn;
      if (ns_next >= 0) {
        f16 hi = (f16)hn;
        XH[(long long)rg*KD + ns_next + o] = hi;
        XL[(long long)rg*KD + ns_next + o] = (f16)(hn - (float)hi);
      }
    }
  }
  if (ns_next >= 0 && lr == 0) {
    #pragma unroll
    for (int reg = 0; reg < 4; ++reg) {
      int rg = rows0 + w*16 + lg*4 + reg;
      int bb = rg >> 9, n = rg & 511;
      if (zero0) {
        XH[(long long)rg*KD] = (f16)0.f;
        XL[(long long)rg*KD] = (f16)0.f;
      } else if (p0) {
        float v = p0[(long long)bb*p0s + n];
        f16 hi = (f16)v;
        XH[(long long)rg*KD] = hi;
        XL[(long long)rg*KD] = (f16)(v - (float)hi);
      }
      if (p1) {
        float v = p1[(long long)bb*p1s + n];
        f16 hi = (f16)v;
        XH[(long long)rg*KD + 1] = hi;
        XL[(long long)rg*KD + 1] = (f16)(v - (float)hi);
      }
    }
  }
}

// ---------------- E_dyn = ne + h @ hyper_W + hyper_b -----------------------------
__global__ __launch_bounds__(256) void edyn_k(
    const float* __restrict__ h, const float* __restrict__ ne,
    const float* __restrict__ hW, const float* __restrict__ hb, float* __restrict__ Ed)
{
  int row = blockIdx.x*4 + (threadIdx.x >> 6);
  int lane = threadIdx.x & 63;
  float hv = h[(long long)row*HH + lane];
  float myval = 0.f;
  #pragma unroll
  for (int e = 0; e < EE; ++e) {
    float v = hv * hW[lane*EE + e];
    #pragma unroll
    for (int off = 32; off >= 1; off >>= 1) v += __shfl_xor(v, off, 64);
    if (lane == e) myval = v;
  }
  if (lane < EE) {
    int n = row & 511;
    Ed[(long long)row*EE + lane] = ne[n*EE + lane] + hb[lane] + myval;
  }
}

// ---------------- go = h @ proj_W + proj_b ; out[:,t]; X col0 for next step ------
__global__ __launch_bounds__(256) void proj_k(
    const float* __restrict__ h, const float* __restrict__ pW, const float* __restrict__ pb,
    float* __restrict__ go, float* __restrict__ out, int t,
    f16* __restrict__ XH, f16* __restrict__ XL, int writeX)
{
  int row = blockIdx.x*4 + (threadIdx.x >> 6);
  int lane = threadIdx.x & 63;
  float v = h[(long long)row*HH + lane] * pW[lane];
  #pragma unroll
  for (int off = 32; off >= 1; off >>= 1) v += __shfl_xor(v, off, 64);
  if (lane == 0) {
    float r = v + pb[0];
    go[row] = r;
    int b = row >> 9, n = row & 511;
    out[((long long)b*TT + t)*NN + n] = r;
    if (writeX) {
      f16 hi = (f16)r;
      XH[(long long)row*KD] = hi;
      XL[(long long)row*KD] = (f16)(r - (float)hi);
    }
  }
}

extern "C" void kernel_launch(void* const* d_in, const int* in_sizes, int n_in,
                              void* d_out, int out_size, void* d_ws, size_t ws_size,
                              hipStream_t stream)
{
  const float* x    = (const float*)d_in[0];
  const float* ycov = (const float*)d_in[1];
  const float* ne   = (const float*)d_in[2];
  const float* egW  = (const float*)d_in[3];
  const float* egb  = (const float*)d_in[4];
  const float* euW  = (const float*)d_in[5];
  const float* eub  = (const float*)d_in[6];
  const float* dgW  = (const float*)d_in[7];
  const float* dgb  = (const float*)d_in[8];
  const float* duW  = (const float*)d_in[9];
  const float* dub  = (const float*)d_in[10];
  const float* pW   = (const float*)d_in[11];
  const float* pb   = (const float*)d_in[12];
  const float* hW   = (const float*)d_in[13];
  const float* hb   = (const float*)d_in[14];
  float* out = (float*)d_out;

  char* p = (char*)d_ws;
  f16* AsH = (f16*)p; p += (size_t)NN*NN*2;
  f16* AsL = (f16*)p; p += (size_t)NN*NN*2;
  f16* AdH = (f16*)p; p += (size_t)NB*NN*NN*2;
  f16* AdL = (f16*)p; p += (size_t)NB*NN*NN*2;
  f16* XH  = (f16*)p; p += (size_t)NB*NN*KD*2;
  f16* XL  = (f16*)p; p += (size_t)NB*NN*KD*2;
  float* h  = (float*)p; p += (size_t)NB*NN*HH*4;
  float* rb = (float*)p; p += (size_t)NB*NN*HH*4;
  float* go = (float*)p; p += (size_t)NB*NN*4;
  float* Ed = (float*)p; p += (size_t)NB*NN*EE*4;
  f16* WgeH = (f16*)p; p += (size_t)128*KD*2;
  f16* WgeL = (f16*)p; p += (size_t)128*KD*2;
  f16* WueH = (f16*)p; p += (size_t)64*KD*2;
  f16* WueL = (f16*)p; p += (size_t)64*KD*2;
  f16* WgdH = (f16*)p; p += (size_t)128*KD*2;
  f16* WgdL = (f16*)p; p += (size_t)128*KD*2;
  f16* WudH = (f16*)p; p += (size_t)64*KD*2;
  f16* WudL = (f16*)p; p += (size_t)64*KD*2;

  fold_w_t<<<(128*KD+255)/256, 256, 0, stream>>>(egW, WgeH, WgeL, 65, 128);
  fold_w_t<<<(64*KD +255)/256, 256, 0, stream>>>(euW, WueH, WueL, 65, 64);
  fold_w_t<<<(128*KD+255)/256, 256, 0, stream>>>(dgW, WgdH, WgdL, 66, 128);
  fold_w_t<<<(64*KD +255)/256, 256, 0, stream>>>(duW, WudH, WudL, 66, 64);

  softmax_graph<<<64, 512, 0, stream>>>(ne, 0, AsH, AsL, 0);
  (void)hipMemsetAsync(h,  0, (size_t)NB*NN*HH*4, stream);
  (void)hipMemsetAsync(go, 0, (size_t)NB*NN*4, stream);
  (void)hipMemsetAsync(XH, 0, (size_t)NB*NN*KD*2*2, stream);  // XH+XL contiguous
  fill_col<<<(NB*NN+255)/256, 256, 0, stream>>>(XH, XL, 0, x, (long long)TTNN);

  dim3 ggrid(NB, 8);
  for (int t = 0; t < TT; ++t) {
    graph_mm_f16<<<ggrid, 256, 0, stream>>>(AsH, AsL, 0, XH, XL, 0);
    graph_mm_f16<<<ggrid, 256, 0, stream>>>(AsH, AsL, 0, XH, XL, 80);
    dense_gate_f16<<<256, 256, 0, stream>>>(XH, XL, WgeH, WgeL, egb, h, rb,
                                            x + (size_t)t*NN, (long long)TTNN,
                                            nullptr, 0, 1);
    graph_mm_f16<<<ggrid, 256, 0, stream>>>(AsH, AsL, 0, XH, XL, 0);
    graph_mm_f16<<<ggrid, 256, 0, stream>>>(AsH, AsL, 0, XH, XL, 80);
    if (t < TT-1)
      dense_upd_f16<<<256, 256, 0, stream>>>(XH, XL, WueH, WueL, eub, rb, h,
                                             1, 0, x + (size_t)(t+1)*NN, (long long)TTNN,
                                             nullptr, 0);
    else
      dense_upd_f16<<<256, 256, 0, stream>>>(XH, XL, WueH, WueL, eub, rb, h,
                                             2, 1, nullptr, 0,
                                             ycov, (long long)TTNN);
  }

  edyn_k<<<NB*NN/4, 256, 0, stream>>>(h, ne, hW, hb, Ed);
  softmax_graph<<<NB*64, 512, 0, stream>>>(Ed, (long long)NN*EE, AdH, AdL, (long long)NN*NN);

  for (int t = 0; t < TT; ++t) {
    graph_mm_f16<<<ggrid, 256, 0, stream>>>(AdH, AdL, (long long)NN*NN, XH, XL, 0);
    graph_mm_f16<<<ggrid, 256, 0, stream>>>(AdH, AdL, (long long)NN*NN, XH, XL, 80);
    dense_gate_f16<<<256, 256, 0, stream>>>(XH, XL, WgdH, WgdL, dgb, h, rb,
                                            go, (long long)NN,
                                            ycov + (size_t)t*NN, (long long)TTNN, 2);
    graph_mm_f16<<<ggrid, 256, 0, stream>>>(AdH, AdL, (long long)NN*NN, XH, XL, 0);
    graph_mm_f16<<<ggrid, 256, 0, stream>>>(AdH, AdL, (long long)NN*NN, XH, XL, 80);
    if (t < TT-1)
      dense_upd_f16<<<256, 256, 0, stream>>>(XH, XL, WudH, WudL, dub, rb, h,
                                             2, 0, nullptr, 0,
                                             ycov + (size_t)(t+1)*NN, (long long)TTNN);
    else
      dense_upd_f16<<<256, 256, 0, stream>>>(XH, XL, WudH, WudL, dub, rb, h,
                                             -1, 0, nullptr, 0, nullptr, 0);
    proj_k<<<NB*NN/4, 256, 0, stream>>>(h, pW, pb, go, out, t, XH, XL, t < TT-1 ? 1 : 0);
  }
}

// Round 5
// 1808.133 us; speedup vs baseline: 7.3003x; 1.1709x over previous
//
#include <hip/hip_runtime.h>

#define NB 32
#define TT 12
#define NN 512
#define HH 64
#define EE 10
#define XS 80       // X row width (halves)
#define KD 240      // dense K = 3*80
#define TTNN (TT*NN)

typedef _Float16 f16;
typedef __attribute__((ext_vector_type(4))) _Float16 f16x4;
typedef __attribute__((ext_vector_type(8))) _Float16 f16x8;
typedef __attribute__((ext_vector_type(4))) float f32x4;

#define MFMA32(a,bb,c) __builtin_amdgcn_mfma_f32_16x16x32_f16(a,bb,c,0,0,0)
#define MFMA16(a,bb,c) __builtin_amdgcn_mfma_f32_16x16x16f16(a,bb,c,0,0,0)

union SMem {
  struct {
    f16 AsH[2][64][32], AsL[2][64][32];   // A tiles
    f16 BsH[2][64][32], BsL[2][64][32];   // A^2 tiles
    f16 XtH[2][80][32], XtL[2][80][32];   // X^T tiles
  } s1;                                    // 53,248 B
  struct {
    f16 gH[64][164], gL[64][164];          // [g1|g2] split, padded stride
    f16 WsH[2][128][20], WsL[2][128][20];  // W chunk dbuf, padded stride
  } s2;                                    // 62,464 B
};

// ---------------- fold Chebyshev into weights; transpose to [O][KD]; f16 split ----
__global__ void fold_w_t(const float* __restrict__ src, f16* __restrict__ WtH,
                         f16* __restrict__ WtL, int C, int O){
  int idx = blockIdx.x*256 + threadIdx.x;
  if (idx >= O*KD) return;
  int o = idx / KD;
  int k = idx % KD;
  int s = k / XS, c = k % XS;
  float v = 0.f;
  if (c < C) {
    if (s == 0)      v = src[c*O+o] - src[(2*C+c)*O+o];
    else if (s == 1) v = src[(C+c)*O+o];
    else             v = 2.f*src[(2*C+c)*O+o];
  }
  f16 hi = (f16)v;
  WtH[idx] = hi;
  WtL[idx] = (f16)(v - (float)hi);
}

// ---------------- A = softmax(relu(E E^T)): 8 rows/block, wave-per-row ----------
__global__ __launch_bounds__(512) void softmax_graph(
    const float* __restrict__ Emb, long long ebs,
    f16* __restrict__ AH, f16* __restrict__ AL, long long abs_)
{
  __shared__ float Es[NN*EE];
  int b  = blockIdx.x >> 6;
  int rt = blockIdx.x & 63;
  const float* Eb = Emb + (long long)b*ebs;
  int tid = threadIdx.x;
  for (int i = tid; i < NN*EE; i += 512) Es[i] = Eb[i];
  __syncthreads();
  int wave = tid >> 6, lane = tid & 63;
  int r = rt*8 + wave;
  float q[EE];
  #pragma unroll
  for (int e = 0; e < EE; ++e) q[e] = Es[r*EE + e];
  float sv[8];
  float mx = 0.f;
  #pragma unroll
  for (int j = 0; j < 8; ++j) {
    int m = 64*j + lane;
    float s = 0.f;
    #pragma unroll
    for (int e = 0; e < EE; ++e) s += q[e]*Es[m*EE + e];
    s = fmaxf(s, 0.f);
    sv[j] = s;
    mx = fmaxf(mx, s);
  }
  #pragma unroll
  for (int off = 32; off >= 1; off >>= 1) mx = fmaxf(mx, __shfl_xor(mx, off, 64));
  float sm = 0.f;
  #pragma unroll
  for (int j = 0; j < 8; ++j) { sv[j] = expf(sv[j] - mx); sm += sv[j]; }
  #pragma unroll
  for (int off = 32; off >= 1; off >>= 1) sm += __shfl_xor(sm, off, 64);
  float inv = 1.f / sm;
  #pragma unroll
  for (int j = 0; j < 8; ++j) {
    int m = 64*j + lane;
    float p = sv[j] * inv;
    long long o = (long long)b*abs_ + (long long)r*NN + m;
    f16 hi = (f16)p;
    AH[o] = hi;
    AL[o] = (f16)(p - (float)hi);
  }
}

// ---------------- B = A @ A (per batch), f16-split 3-product ---------------------
__global__ __launch_bounds__(256) void sq_mm(
    const f16* __restrict__ AH, const f16* __restrict__ AL, long long astr,
    f16* __restrict__ BH, f16* __restrict__ BL, long long bstr)
{
  __shared__ f16 RsH[64][32], RsL[64][32], CsH[64][32], CsL[64][32];
  int b = blockIdx.z;
  int rows0 = blockIdx.y*64, cols0 = blockIdx.x*64;
  const f16* Ah = AH + (long long)b*astr;
  const f16* Al = AL + (long long)b*astr;
  int tid = threadIdx.x, l = tid & 63, w = tid >> 6, lr = l & 15, lg = l >> 4;
  int ar = w*16 + lr, asw = (ar>>2)&3;
  int st_row = tid >> 2, st_seg = tid & 3, a_sw = (st_row>>2)&3;
  int sx_m = tid >> 3, sx_sub = tid & 7;
  f32x4 acc[4] = {};
  for (int kt = 0; kt < 16; ++kt) {
    int k0 = kt*32;
    __syncthreads();
    {
      f16x8 vh = *(const f16x8*)&Ah[(long long)(rows0+st_row)*NN + k0 + 8*st_seg];
      f16x8 vl = *(const f16x8*)&Al[(long long)(rows0+st_row)*NN + k0 + 8*st_seg];
      *(f16x8*)&RsH[st_row][8*(st_seg ^ a_sw)] = vh;
      *(f16x8*)&RsL[st_row][8*(st_seg ^ a_sw)] = vl;
    }
    #pragma unroll
    for (int j = 0; j < 2; ++j) {
      int c4 = sx_sub + 8*j;   // 0..15
      f16x4 vh = *(const f16x4*)&Ah[(long long)(k0+sx_m)*NN + cols0 + 4*c4];
      f16x4 vl = *(const f16x4*)&Al[(long long)(k0+sx_m)*NN + cols0 + 4*c4];
      int mm = sx_m ^ (8*(c4 & 3));
      #pragma unroll
      for (int q = 0; q < 4; ++q) {
        CsH[4*c4+q][mm] = vh[q];
        CsL[4*c4+q][mm] = vl[q];
      }
    }
    __syncthreads();
    f16x8 a_h = *(const f16x8*)&RsH[ar][8*(lg ^ asw)];
    f16x8 a_l = *(const f16x8*)&RsL[ar][8*(lg ^ asw)];
    #pragma unroll
    for (int cf = 0; cf < 4; ++cf) {
      int c = cf*16 + lr;
      int sx = 8*(lg ^ ((c>>2)&3));
      f16x8 b_h = *(const f16x8*)&CsH[c][sx];
      f16x8 b_l = *(const f16x8*)&CsL[c][sx];
      acc[cf] = MFMA32(a_h, b_h, acc[cf]);
      acc[cf] = MFMA32(a_h, b_l, acc[cf]);
      acc[cf] = MFMA32(a_l, b_h, acc[cf]);
    }
  }
  #pragma unroll
  for (int cf = 0; cf < 4; ++cf) {
    #pragma unroll
    for (int reg = 0; reg < 4; ++reg) {
      int r = rows0 + w*16 + lg*4 + reg;
      int c = cols0 + cf*16 + lr;
      float v = acc[cf][reg];
      f16 hi = (f16)v;
      long long o = (long long)b*bstr + (long long)r*NN + c;
      BH[o] = hi;
      BL[o] = (f16)(v - (float)hi);
    }
  }
}

// ---------------- write one special column of X (split) -------------------------
__global__ void fill_col(f16* __restrict__ XH, f16* __restrict__ XL, int col,
                         const float* __restrict__ src, long long sstr){
  int row = blockIdx.x*256 + threadIdx.x;
  if (row >= NB*NN) return;
  float v = src[(long long)(row>>9)*sstr + (row & 511)];
  f16 hi = (f16)v;
  XH[(long long)row*XS + col] = hi;
  XL[(long long)row*XS + col] = (f16)(v - (float)hi);
}

// ---------------- fused half-step: AGCN(g1=A·x, g2=A²·x) + dense + epilogue -----
// GATE=1: zr=sigmoid(...); write z*h into Xout[ns..], r into rb; copy specials.
// GATE=0: h=r*h+(1-r)*tanh(...); write next-inp into Xout; DEC: proj->out/go.
template<int GATE, int DEC>
__global__ __launch_bounds__(256) void fused_half(
    const f16* __restrict__ AH, const f16* __restrict__ AL,
    const f16* __restrict__ A2H, const f16* __restrict__ A2L, long long astr,
    const f16* __restrict__ XinH, const f16* __restrict__ XinL,
    f16* __restrict__ XoutH, f16* __restrict__ XoutL,
    const f16* __restrict__ WH, const f16* __restrict__ WL,
    const float* __restrict__ bias,
    float* __restrict__ hbuf, float* __restrict__ rb,
    const float* __restrict__ pWv, const float* __restrict__ pbv,
    float* __restrict__ outp, int t,
    const float* __restrict__ s0src, const float* __restrict__ s1src,
    int ns, int ns_next, int writeX)
{
  __shared__ SMem sm;
  const int b = blockIdx.x;
  const int rows0 = blockIdx.y * 64;
  const f16* Ah  = AH  + (long long)b*astr + (long long)rows0*NN;
  const f16* Al_ = AL  + (long long)b*astr + (long long)rows0*NN;
  const f16* Bh  = A2H + (long long)b*astr + (long long)rows0*NN;
  const f16* Bl  = A2L + (long long)b*astr + (long long)rows0*NN;
  const f16* Xh  = XinH + (long long)b*NN*XS;
  const f16* Xl  = XinL + (long long)b*NN*XS;
  const int tid = threadIdx.x;
  const int l = tid & 63, w = tid >> 6;
  const int lr = l & 15, lg = l >> 4;
  const int ar = w*16 + lr, asw = (ar>>2)&3;
  const int st_row = tid >> 2, st_seg = tid & 3, a_sw = (st_row>>2)&3;
  const int sx_m = tid >> 3, sx_sub = tid & 7;

  f32x4 acc1[5] = {}, acc2[5] = {};
  f16x8 a0[4], a1[4];
  f16x4 x0[3][2], x1[3][2];

  auto LOAD = [&](int kt, f16x8 (&a)[4], f16x4 (&xx)[3][2]) {
    int k0 = kt*32;
    long long aoff = (long long)st_row*NN + k0 + 8*st_seg;
    a[0] = *(const f16x8*)&Ah [aoff];
    a[1] = *(const f16x8*)&Al_[aoff];
    a[2] = *(const f16x8*)&Bh [aoff];
    a[3] = *(const f16x8*)&Bl [aoff];
    #pragma unroll
    for (int j = 0; j < 3; ++j) {
      int c4 = sx_sub + 8*j;
      if (c4 < 20) {
        long long xoff = (long long)(k0 + sx_m)*XS + 4*c4;
        xx[j][0] = *(const f16x4*)&Xh[xoff];
        xx[j][1] = *(const f16x4*)&Xl[xoff];
      }
    }
  };
  auto STORE = [&](int buf, f16x8 (&a)[4], f16x4 (&xx)[3][2]) {
    int sc = 8*(st_seg ^ a_sw);
    *(f16x8*)&sm.s1.AsH[buf][st_row][sc] = a[0];
    *(f16x8*)&sm.s1.AsL[buf][st_row][sc] = a[1];
    *(f16x8*)&sm.s1.BsH[buf][st_row][sc] = a[2];
    *(f16x8*)&sm.s1.BsL[buf][st_row][sc] = a[3];
    #pragma unroll
    for (int j = 0; j < 3; ++j) {
      int c4 = sx_sub + 8*j;
      if (c4 < 20) {
        int mm = sx_m ^ (8*(c4 & 3));
        #pragma unroll
        for (int q = 0; q < 4; ++q) {
          sm.s1.XtH[buf][4*c4+q][mm] = xx[j][0][q];
          sm.s1.XtL[buf][4*c4+q][mm] = xx[j][1][q];
        }
      }
    }
  };
  auto COMP = [&](int buf) {
    int sa = 8*(lg ^ asw);
    f16x8 a1h = *(const f16x8*)&sm.s1.AsH[buf][ar][sa];
    f16x8 a1l = *(const f16x8*)&sm.s1.AsL[buf][ar][sa];
    f16x8 a2h = *(const f16x8*)&sm.s1.BsH[buf][ar][sa];
    f16x8 a2l = *(const f16x8*)&sm.s1.BsL[buf][ar][sa];
    #pragma unroll
    for (int cf = 0; cf < 5; ++cf) {
      int c = cf*16 + lr;
      int sx = 8*(lg ^ ((c>>2)&3));
      f16x8 b_h = *(const f16x8*)&sm.s1.XtH[buf][c][sx];
      f16x8 b_l = *(const f16x8*)&sm.s1.XtL[buf][c][sx];
      acc1[cf] = MFMA32(a1h, b_h, acc1[cf]);
      acc1[cf] = MFMA32(a1h, b_l, acc1[cf]);
      acc1[cf] = MFMA32(a1l, b_h, acc1[cf]);
      acc2[cf] = MFMA32(a2h, b_h, acc2[cf]);
      acc2[cf] = MFMA32(a2h, b_l, acc2[cf]);
      acc2[cf] = MFMA32(a2l, b_h, acc2[cf]);
    }
  };

  LOAD(0, a0, x0);
  LOAD(1, a1, x1);
  STORE(0, a0, x0);
  __syncthreads();
  #pragma unroll
  for (int kt2 = 0; kt2 < 8; ++kt2) {
    int kt = kt2*2;
    if (kt+2 < 16) LOAD(kt+2, a0, x0);
    COMP(0);
    STORE(1, a1, x1);
    __syncthreads();
    if (kt+3 < 16) LOAD(kt+3, a1, x1);
    COMP(1);
    if (kt+2 < 16) STORE(0, a0, x0);
    __syncthreads();
  }

  // ---- dump g1,g2 (split) into LDS; staging region is dead now ----
  #pragma unroll
  for (int cf = 0; cf < 5; ++cf) {
    int col = cf*16 + lr;
    #pragma unroll
    for (int reg = 0; reg < 4; ++reg) {
      int row = w*16 + lg*4 + reg;
      float v1 = acc1[cf][reg]; f16 h1 = (f16)v1;
      sm.s2.gH[row][col] = h1;
      sm.s2.gL[row][col] = (f16)(v1 - (float)h1);
      float v2 = acc2[cf][reg]; f16 h2 = (f16)v2;
      sm.s2.gH[row][80+col] = h2;
      sm.s2.gL[row][80+col] = (f16)(v2 - (float)h2);
    }
  }

  // ---- dense: acc over K = [x(80, global) | g1(80, LDS) | g2(80, LDS)] ----
  constexpr int NCF = GATE ? 8 : 4;
  constexpr int OO  = GATE ? 128 : 64;
  f32x4 accD[NCF] = {};
  const long long arowg = (long long)b*NN + rows0 + w*16 + lr;
  const f16* xrowH = XinH + arowg*XS;
  const f16* xrowL = XinL + arowg*XS;

  auto stageW = [&](int c, int buf) {
    if (tid < 2*OO) {
      int o = tid >> 1, seg = tid & 1;
      long long woff = (long long)o*KD + c*16 + 8*seg;
      *(f16x8*)&sm.s2.WsH[buf][o][8*seg] = *(const f16x8*)&WH[woff];
      *(f16x8*)&sm.s2.WsL[buf][o][8*seg] = *(const f16x8*)&WL[woff];
    }
  };
  stageW(0, 0);
  #pragma unroll
  for (int c = 0; c < 15; ++c) {
    __syncthreads();
    if (c < 14) stageW(c+1, (c+1)&1);
    int k0 = c*16;
    f16x4 a_h, a_l;
    if (k0 < 80) {
      a_h = *(const f16x4*)&xrowH[k0 + 4*lg];
      a_l = *(const f16x4*)&xrowL[k0 + 4*lg];
    } else {
      int gk = k0 - 80 + 4*lg;
      a_h = *(const f16x4*)&sm.s2.gH[w*16 + lr][gk];
      a_l = *(const f16x4*)&sm.s2.gL[w*16 + lr][gk];
    }
    #pragma unroll
    for (int cf = 0; cf < NCF; ++cf) {
      f16x4 b_h = *(const f16x4*)&sm.s2.WsH[c&1][cf*16 + lr][4*lg];
      f16x4 b_l = *(const f16x4*)&sm.s2.WsL[c&1][cf*16 + lr][4*lg];
      accD[cf] = MFMA16(a_h, b_h, accD[cf]);
      accD[cf] = MFMA16(a_h, b_l, accD[cf]);
      accD[cf] = MFMA16(a_l, b_h, accD[cf]);
    }
  }

  // ---- epilogue ----
  if constexpr (GATE) {
    #pragma unroll
    for (int cf = 0; cf < 8; ++cf) {
      int o = cf*16 + lr;
      float bi = bias[o];
      #pragma unroll
      for (int reg = 0; reg < 4; ++reg) {
        long long grow = (long long)b*NN + rows0 + w*16 + lg*4 + reg;
        float v = 1.f/(1.f + expf(-(accD[cf][reg] + bi)));
        if (o < HH) {
          float zh = v * hbuf[grow*HH + o];
          f16 hi = (f16)zh;
          XoutH[grow*XS + ns + o] = hi;
          XoutL[grow*XS + ns + o] = (f16)(zh - (float)hi);
        } else {
          rb[grow*HH + (o - HH)] = v;
        }
      }
    }
    if (lr < ns) {
      #pragma unroll
      for (int reg = 0; reg < 4; ++reg) {
        long long grow = (long long)b*NN + rows0 + w*16 + lg*4 + reg;
        XoutH[grow*XS + lr] = XinH[grow*XS + lr];
        XoutL[grow*XS + lr] = XinL[grow*XS + lr];
      }
    }
  } else {
    float gop[4] = {0.f, 0.f, 0.f, 0.f};
    #pragma unroll
    for (int cf = 0; cf < 4; ++cf) {
      int o = cf*16 + lr;
      float bi = bias[o];
      float pwv = 0.f;
      if constexpr (DEC) pwv = pWv[o];
      #pragma unroll
      for (int reg = 0; reg < 4; ++reg) {
        long long grow = (long long)b*NN + rows0 + w*16 + lg*4 + reg;
        float hc = tanhf(accD[cf][reg] + bi);
        float rv = rb[grow*HH + o];
        float hv = hbuf[grow*HH + o];
        float hn = rv*hv + (1.f - rv)*hc;
        hbuf[grow*HH + o] = hn;
        if (writeX) {
          f16 hi = (f16)hn;
          XoutH[grow*XS + ns_next + o] = hi;
          XoutL[grow*XS + ns_next + o] = (f16)(hn - (float)hi);
        }
        if constexpr (DEC) gop[reg] += hn * pwv;
      }
    }
    if constexpr (DEC) {
      #pragma unroll
      for (int reg = 0; reg < 4; ++reg) {
        #pragma unroll
        for (int off = 8; off >= 1; off >>= 1)
          gop[reg] += __shfl_xor(gop[reg], off, 64);
      }
      if (lr == 0) {
        float pbv0 = pbv[0];
        #pragma unroll
        for (int reg = 0; reg < 4; ++reg) {
          int n = rows0 + w*16 + lg*4 + reg;
          float go = gop[reg] + pbv0;
          outp[((long long)b*TT + t)*NN + n] = go;
          if (writeX) {
            long long grow = (long long)b*NN + n;
            f16 hi = (f16)go;
            XoutH[grow*XS] = hi;
            XoutL[grow*XS] = (f16)(go - (float)hi);
            float yv = s1src[(long long)b*TTNN + n];
            f16 hy = (f16)yv;
            XoutH[grow*XS + 1] = hy;
            XoutL[grow*XS + 1] = (f16)(yv - (float)hy);
          }
        }
      }
    } else {
      if (writeX && lr == 0) {
        #pragma unroll
        for (int reg = 0; reg < 4; ++reg) {
          int n = rows0 + w*16 + lg*4 + reg;
          long long grow = (long long)b*NN + n;
          float v0 = s0src ? s0src[(long long)b*TTNN + n] : 0.f;
          f16 h0 = (f16)v0;
          XoutH[grow*XS] = h0;
          XoutL[grow*XS] = (f16)(v0 - (float)h0);
          if (ns_next == 2 && s1src) {
            float v1 = s1src[(long long)b*TTNN + n];
            f16 h1 = (f16)v1;
            XoutH[grow*XS + 1] = h1;
            XoutL[grow*XS + 1] = (f16)(v1 - (float)h1);
          }
        }
      }
    }
  }
}

// ---------------- E_dyn = ne + h @ hyper_W + hyper_b -----------------------------
__global__ __launch_bounds__(256) void edyn_k(
    const float* __restrict__ h, const float* __restrict__ ne,
    const float* __restrict__ hW, const float* __restrict__ hb, float* __restrict__ Ed)
{
  int row = blockIdx.x*4 + (threadIdx.x >> 6);
  int lane = threadIdx.x & 63;
  float hv = h[(long long)row*HH + lane];
  float myval = 0.f;
  #pragma unroll
  for (int e = 0; e < EE; ++e) {
    float v = hv * hW[lane*EE + e];
    #pragma unroll
    for (int off = 32; off >= 1; off >>= 1) v += __shfl_xor(v, off, 64);
    if (lane == e) myval = v;
  }
  if (lane < EE) {
    int n = row & 511;
    Ed[(long long)row*EE + lane] = ne[n*EE + lane] + hb[lane] + myval;
  }
}

extern "C" void kernel_launch(void* const* d_in, const int* in_sizes, int n_in,
                              void* d_out, int out_size, void* d_ws, size_t ws_size,
                              hipStream_t stream)
{
  const float* x    = (const float*)d_in[0];
  const float* ycov = (const float*)d_in[1];
  const float* ne   = (const float*)d_in[2];
  const float* egW  = (const float*)d_in[3];
  const float* egb  = (const float*)d_in[4];
  const float* euW  = (const float*)d_in[5];
  const float* eub  = (const float*)d_in[6];
  const float* dgW  = (const float*)d_in[7];
  const float* dgb  = (const float*)d_in[8];
  const float* duW  = (const float*)d_in[9];
  const float* dub  = (const float*)d_in[10];
  const float* pW   = (const float*)d_in[11];
  const float* pb   = (const float*)d_in[12];
  const float* hW   = (const float*)d_in[13];
  const float* hb   = (const float*)d_in[14];
  float* out = (float*)d_out;

  char* p = (char*)d_ws;
  f16* AsH  = (f16*)p; p += (size_t)NN*NN*2;
  f16* AsL  = (f16*)p; p += (size_t)NN*NN*2;
  f16* As2H = (f16*)p; p += (size_t)NN*NN*2;
  f16* As2L = (f16*)p; p += (size_t)NN*NN*2;
  f16* AdH  = (f16*)p; p += (size_t)NB*NN*NN*2;
  f16* AdL  = (f16*)p; p += (size_t)NB*NN*NN*2;
  f16* Ad2H = (f16*)p; p += (size_t)NB*NN*NN*2;
  f16* Ad2L = (f16*)p; p += (size_t)NB*NN*NN*2;
  f16* XaH  = (f16*)p; p += (size_t)NB*NN*XS*2;
  f16* XaL  = (f16*)p; p += (size_t)NB*NN*XS*2;
  f16* XbH  = (f16*)p; p += (size_t)NB*NN*XS*2;
  f16* XbL  = (f16*)p; p += (size_t)NB*NN*XS*2;
  float* h  = (float*)p; p += (size_t)NB*NN*HH*4;
  float* rb = (float*)p; p += (size_t)NB*NN*HH*4;
  float* Ed = (float*)p; p += (size_t)NB*NN*EE*4;
  f16* WgeH = (f16*)p; p += (size_t)128*KD*2;
  f16* WgeL = (f16*)p; p += (size_t)128*KD*2;
  f16* WueH = (f16*)p; p += (size_t)64*KD*2;
  f16* WueL = (f16*)p; p += (size_t)64*KD*2;
  f16* WgdH = (f16*)p; p += (size_t)128*KD*2;
  f16* WgdL = (f16*)p; p += (size_t)128*KD*2;
  f16* WudH = (f16*)p; p += (size_t)64*KD*2;
  f16* WudL = (f16*)p; p += (size_t)64*KD*2;

  fold_w_t<<<(128*KD+255)/256, 256, 0, stream>>>(egW, WgeH, WgeL, 65, 128);
  fold_w_t<<<(64*KD +255)/256, 256, 0, stream>>>(euW, WueH, WueL, 65, 64);
  fold_w_t<<<(128*KD+255)/256, 256, 0, stream>>>(dgW, WgdH, WgdL, 66, 128);
  fold_w_t<<<(64*KD +255)/256, 256, 0, stream>>>(duW, WudH, WudL, 66, 64);

  softmax_graph<<<64, 512, 0, stream>>>(ne, 0, AsH, AsL, 0);
  sq_mm<<<dim3(8,8,1), 256, 0, stream>>>(AsH, AsL, 0, As2H, As2L, 0);
  (void)hipMemsetAsync(h, 0, (size_t)NB*NN*HH*4, stream);
  (void)hipMemsetAsync(XaH, 0, (size_t)NB*NN*XS*2*4, stream);  // XaH..XbL contiguous
  fill_col<<<(NB*NN+255)/256, 256, 0, stream>>>(XaH, XaL, 0, x, (long long)TTNN);

  dim3 fgrid(NB, 8);
  for (int t = 0; t < TT; ++t) {
    fused_half<1,0><<<fgrid, 256, 0, stream>>>(
        AsH, AsL, As2H, As2L, 0, XaH, XaL, XbH, XbL,
        WgeH, WgeL, egb, h, rb, nullptr, nullptr, nullptr, t,
        nullptr, nullptr, 1, 0, 1);
    fused_half<0,0><<<fgrid, 256, 0, stream>>>(
        AsH, AsL, As2H, As2L, 0, XbH, XbL, XaH, XaL,
        WueH, WueL, eub, h, rb, nullptr, nullptr, nullptr, t,
        (t < TT-1 ? x + (size_t)(t+1)*NN : nullptr),
        (t < TT-1 ? nullptr : ycov),
        1, (t < TT-1 ? 1 : 2), 1);
  }

  edyn_k<<<NB*NN/4, 256, 0, stream>>>(h, ne, hW, hb, Ed);
  softmax_graph<<<NB*64, 512, 0, stream>>>(Ed, (long long)NN*EE, AdH, AdL, (long long)NN*NN);
  sq_mm<<<dim3(8,8,NB), 256, 0, stream>>>(AdH, AdL, (long long)NN*NN, Ad2H, Ad2L, (long long)NN*NN);

  for (int t = 0; t < TT; ++t) {
    fused_half<1,1><<<fgrid, 256, 0, stream>>>(
        AdH, AdL, Ad2H, Ad2L, (long long)NN*NN, XaH, XaL, XbH, XbL,
        WgdH, WgdL, dgb, h, rb, nullptr, nullptr, nullptr, t,
        nullptr, nullptr, 2, 0, 1);
    fused_half<0,1><<<fgrid, 256, 0, stream>>>(
        AdH, AdL, Ad2H, Ad2L, (long long)NN*NN, XbH, XbL, XaH, XaL,
        WudH, WudL, dub, h, rb, pW, pb, out, t,
        nullptr, (t < TT-1 ? ycov + (size_t)(t+1)*NN : nullptr),
        2, 2, (t < TT-1 ? 1 : 0));
  }
}

// Round 6
// 1718.178 us; speedup vs baseline: 7.6825x; 1.0524x over previous
//
#include <hip/hip_runtime.h>

#define NB 32
#define TT 12
#define NN 512
#define HH 64
#define EE 10
#define XS 80       // X row width (halves)
#define KD 240      // dense K = 3*80
#define RS (NB*NN)  // 16384 global rows
#define TTNN (TT*NN)
#define XPAD 40
#define GP 164

typedef _Float16 f16;
typedef __attribute__((ext_vector_type(4))) _Float16 f16x4;
typedef __attribute__((ext_vector_type(8))) _Float16 f16x8;
typedef __attribute__((ext_vector_type(4))) float f32x4;

#define MFMA32(a,bb,c) __builtin_amdgcn_mfma_f32_16x16x32_f16(a,bb,c,0,0,0)
#define MFMA16(a,bb,c) __builtin_amdgcn_mfma_f32_16x16x16f16(a,bb,c,0,0,0)

union SMem {
  struct {
    f16 PsH[2][2][64][32], PsL[2][2][64][32];  // [buf][A=0/A2=1][row][k]
    f16 XtH[2][80][XPAD], XtL[2][80][XPAD];    // [buf][col][k]
  } s1;  // 32KB + 25.6KB = 57.6KB
  struct {
    f16 gH[64][GP], gL[64][GP];                // [row][g1|g2]
  } s2;  // 42KB
};

// ---------------- fold Chebyshev into weights; transpose to [O][KD]; f16 split ----
__global__ void fold_w_t(const float* __restrict__ src, f16* __restrict__ WtH,
                         f16* __restrict__ WtL, int C, int O){
  int idx = blockIdx.x*256 + threadIdx.x;
  if (idx >= O*KD) return;
  int o = idx / KD;
  int k = idx % KD;
  int s = k / XS, c = k % XS;
  float v = 0.f;
  if (c < C) {
    if (s == 0)      v = src[c*O+o] - src[(2*C+c)*O+o];
    else if (s == 1) v = src[(C+c)*O+o];
    else             v = 2.f*src[(2*C+c)*O+o];
  }
  f16 hi = (f16)v;
  WtH[idx] = hi;
  WtL[idx] = (f16)(v - (float)hi);
}

// ---------------- A = softmax(relu(E E^T)): 8 rows/block, wave-per-row ----------
__global__ __launch_bounds__(512) void softmax_graph(
    const float* __restrict__ Emb, long long ebs,
    f16* __restrict__ AH, f16* __restrict__ AL, long long abs_)
{
  __shared__ float Es[NN*EE];
  int b  = blockIdx.x >> 6;
  int rt = blockIdx.x & 63;
  const float* Eb = Emb + (long long)b*ebs;
  int tid = threadIdx.x;
  for (int i = tid; i < NN*EE; i += 512) Es[i] = Eb[i];
  __syncthreads();
  int wave = tid >> 6, lane = tid & 63;
  int r = rt*8 + wave;
  float q[EE];
  #pragma unroll
  for (int e = 0; e < EE; ++e) q[e] = Es[r*EE + e];
  float sv[8];
  float mx = 0.f;
  #pragma unroll
  for (int j = 0; j < 8; ++j) {
    int m = 64*j + lane;
    float s = 0.f;
    #pragma unroll
    for (int e = 0; e < EE; ++e) s += q[e]*Es[m*EE + e];
    s = fmaxf(s, 0.f);
    sv[j] = s;
    mx = fmaxf(mx, s);
  }
  #pragma unroll
  for (int off = 32; off >= 1; off >>= 1) mx = fmaxf(mx, __shfl_xor(mx, off, 64));
  float sm = 0.f;
  #pragma unroll
  for (int j = 0; j < 8; ++j) { sv[j] = expf(sv[j] - mx); sm += sv[j]; }
  #pragma unroll
  for (int off = 32; off >= 1; off >>= 1) sm += __shfl_xor(sm, off, 64);
  float inv = 1.f / sm;
  #pragma unroll
  for (int j = 0; j < 8; ++j) {
    int m = 64*j + lane;
    float p = sv[j] * inv;
    long long o = (long long)b*abs_ + (long long)r*NN + m;
    f16 hi = (f16)p;
    AH[o] = hi;
    AL[o] = (f16)(p - (float)hi);
  }
}

// ---------------- B = A @ A (per batch), f16-split 3-product ---------------------
__global__ __launch_bounds__(256) void sq_mm(
    const f16* __restrict__ AH, const f16* __restrict__ AL, long long astr,
    f16* __restrict__ BH, f16* __restrict__ BL, long long bstr)
{
  __shared__ f16 RsH[64][32], RsL[64][32], CsH[64][34], CsL[64][34];
  int b = blockIdx.z;
  int rows0 = blockIdx.y*64, cols0 = blockIdx.x*64;
  const f16* Ah = AH + (long long)b*astr;
  const f16* Al = AL + (long long)b*astr;
  int tid = threadIdx.x, l = tid & 63, w = tid >> 6, lr = l & 15, lg = l >> 4;
  int ar = w*16 + lr, asw = (ar>>2)&3;
  int st_row = tid >> 2, st_seg = tid & 3, a_sw = (st_row>>2)&3;
  int sx_m = tid >> 3, sx_sub = tid & 7;
  f32x4 acc[4] = {};
  for (int kt = 0; kt < 16; ++kt) {
    int k0 = kt*32;
    __syncthreads();
    {
      f16x8 vh = *(const f16x8*)&Ah[(long long)(rows0+st_row)*NN + k0 + 8*st_seg];
      f16x8 vl = *(const f16x8*)&Al[(long long)(rows0+st_row)*NN + k0 + 8*st_seg];
      *(f16x8*)&RsH[st_row][8*(st_seg ^ a_sw)] = vh;
      *(f16x8*)&RsL[st_row][8*(st_seg ^ a_sw)] = vl;
    }
    #pragma unroll
    for (int j = 0; j < 2; ++j) {
      int c4 = sx_sub + 8*j;   // 0..15
      f16x4 vh = *(const f16x4*)&Ah[(long long)(k0+sx_m)*NN + cols0 + 4*c4];
      f16x4 vl = *(const f16x4*)&Al[(long long)(k0+sx_m)*NN + cols0 + 4*c4];
      #pragma unroll
      for (int q = 0; q < 4; ++q) {
        CsH[4*c4+q][sx_m] = vh[q];
        CsL[4*c4+q][sx_m] = vl[q];
      }
    }
    __syncthreads();
    f16x8 a_h = *(const f16x8*)&RsH[ar][8*(lg ^ asw)];
    f16x8 a_l = *(const f16x8*)&RsL[ar][8*(lg ^ asw)];
    #pragma unroll
    for (int cf = 0; cf < 4; ++cf) {
      int c = cf*16 + lr;
      f16x8 b_h = *(const f16x8*)&CsH[c][8*lg];
      f16x8 b_l = *(const f16x8*)&CsL[c][8*lg];
      acc[cf] = MFMA32(a_h, b_h, acc[cf]);
      acc[cf] = MFMA32(a_h, b_l, acc[cf]);
      acc[cf] = MFMA32(a_l, b_h, acc[cf]);
    }
  }
  #pragma unroll
  for (int cf = 0; cf < 4; ++cf) {
    #pragma unroll
    for (int reg = 0; reg < 4; ++reg) {
      int r = rows0 + w*16 + lg*4 + reg;
      int c = cols0 + cf*16 + lr;
      float v = acc[cf][reg];
      f16 hi = (f16)v;
      long long o = (long long)b*bstr + (long long)r*NN + c;
      BH[o] = hi;
      BL[o] = (f16)(v - (float)hi);
    }
  }
}

// ---------------- write one special column of X (dual layout, split) -------------
__global__ void fill_col(f16* __restrict__ XRH, f16* __restrict__ XRL,
                         f16* __restrict__ XCH, f16* __restrict__ XCL, int col,
                         const float* __restrict__ src, long long sstr){
  int row = blockIdx.x*256 + threadIdx.x;
  if (row >= RS) return;
  float v = src[(long long)(row>>9)*sstr + (row & 511)];
  f16 hi = (f16)v;
  f16 lo = (f16)(v - (float)hi);
  XRH[(long long)row*XS + col] = hi;
  XRL[(long long)row*XS + col] = lo;
  XCH[(long long)col*RS + row] = hi;
  XCL[(long long)col*RS + row] = lo;
}

// ---------------- fused half-step: 8 waves; grp0: g1=A·x, grp1: g2=A²·x ---------
// then dense (+W from global) and epilogue.
template<int GATE, int DEC>
__global__ __launch_bounds__(512, 2) void fused_half(
    const f16* __restrict__ AH, const f16* __restrict__ AL,
    const f16* __restrict__ A2H, const f16* __restrict__ A2L, long long astr,
    const f16* __restrict__ XiRH, const f16* __restrict__ XiRL,
    const f16* __restrict__ XiCH, const f16* __restrict__ XiCL,
    f16* __restrict__ XoRH, f16* __restrict__ XoRL,
    f16* __restrict__ XoCH, f16* __restrict__ XoCL,
    const f16* __restrict__ WH, const f16* __restrict__ WL,
    const float* __restrict__ bias,
    float* __restrict__ hbuf, float* __restrict__ rb,
    const float* __restrict__ pWv, const float* __restrict__ pbv,
    float* __restrict__ outp, int t,
    const float* __restrict__ s0src, const float* __restrict__ s1src,
    int ns, int ns_next, int writeX)
{
  __shared__ SMem sm;
  __shared__ float gpart[64];
  const int b = blockIdx.x;
  const int rows0 = blockIdx.y * 64;
  const long long bNN = (long long)b*NN;
  const int tid = threadIdx.x;
  const int w = tid >> 6, l = tid & 63;
  const int lr = l & 15, lg = l >> 4;
  const int grp = w >> 2;
  const int w4 = w & 3;
  const int ar = w4*16 + lr;
  const int asw = (ar >> 2) & 3;

  // A/A2 staging mapping: tid<256 stages A, tid>=256 stages A2
  const int stw = (tid < 256) ? 0 : 1;
  const int at = tid & 255;
  const int st_row = at >> 2, st_seg = at & 3;
  const int a_sw = (st_row >> 2) & 3;
  const f16* PgH = (stw ? A2H : AH) + (long long)b*astr + (long long)rows0*NN;
  const f16* PgL = (stw ? A2L : AL) + (long long)b*astr + (long long)rows0*NN;

  // X staging mapping (col-major source): 512 thr cover cols 0..63; first 128 also 64..79
  const int xc = tid >> 3;
  const int xsub = tid & 7;
  const int xa = xsub >> 2;
  const int xo = xsub & 3;
  const int xc2 = (tid < 128) ? (64 + xc) : 64;
  const f16* XC1 = (xa ? XiCL : XiCH) + (long long)xc*RS + bNN;
  const f16* XC2 = (xa ? XiCL : XiCH) + (long long)xc2*RS + bNN;

  f16x8 rH0{}, rL0{}, x10{}, x20{}, rH1{}, rL1{}, x11{}, x21{};

  auto LOAD = [&](int kt, f16x8& rH, f16x8& rL, f16x8& x1, f16x8& x2){
    int k0 = kt*32;
    long long ao = (long long)st_row*NN + k0 + 8*st_seg;
    rH = *(const f16x8*)&PgH[ao];
    rL = *(const f16x8*)&PgL[ao];
    x1 = *(const f16x8*)&XC1[k0 + 8*xo];
    if (tid < 128) x2 = *(const f16x8*)&XC2[k0 + 8*xo];
  };
  auto STORE = [&](int buf, f16x8& rH, f16x8& rL, f16x8& x1, f16x8& x2){
    int sc = 8*(st_seg ^ a_sw);
    *(f16x8*)&sm.s1.PsH[buf][stw][st_row][sc] = rH;
    *(f16x8*)&sm.s1.PsL[buf][stw][st_row][sc] = rL;
    f16 (*xt)[XPAD] = xa ? sm.s1.XtL[buf] : sm.s1.XtH[buf];
    *(f16x8*)&xt[xc][8*xo] = x1;
    if (tid < 128) *(f16x8*)&xt[64 + xc][8*xo] = x2;
  };
  f32x4 acc[5] = {};
  auto COMP = [&](int buf){
    int sa = 8*(lg ^ asw);
    f16x8 ah = *(const f16x8*)&sm.s1.PsH[buf][grp][ar][sa];
    f16x8 al2 = *(const f16x8*)&sm.s1.PsL[buf][grp][ar][sa];
    #pragma unroll
    for (int cf = 0; cf < 5; ++cf) {
      int c = cf*16 + lr;
      f16x8 bh = *(const f16x8*)&sm.s1.XtH[buf][c][8*lg];
      f16x8 bl = *(const f16x8*)&sm.s1.XtL[buf][c][8*lg];
      acc[cf] = MFMA32(ah, bh, acc[cf]);
      acc[cf] = MFMA32(ah, bl, acc[cf]);
      acc[cf] = MFMA32(al2, bh, acc[cf]);
    }
  };

  LOAD(0, rH0,rL0,x10,x20);
  LOAD(1, rH1,rL1,x11,x21);
  STORE(0, rH0,rL0,x10,x20);
  __syncthreads();
  #pragma unroll
  for (int kt2 = 0; kt2 < 8; ++kt2) {
    int kt = kt2*2;
    if (kt+2 < 16) LOAD(kt+2, rH0,rL0,x10,x20);
    COMP(0);
    STORE(1, rH1,rL1,x11,x21);
    __syncthreads();
    if (kt+3 < 16) LOAD(kt+3, rH1,rL1,x11,x21);
    COMP(1);
    if (kt+2 < 16) STORE(0, rH0,rL0,x10,x20);
    __syncthreads();
  }

  // ---- dump g (split) into LDS union (staging dead after final barrier) ----
  {
    int go_ = grp*80;
    #pragma unroll
    for (int cf = 0; cf < 5; ++cf) {
      int col = go_ + cf*16 + lr;
      #pragma unroll
      for (int reg = 0; reg < 4; ++reg) {
        int row = w4*16 + lg*4 + reg;
        float v = acc[cf][reg];
        f16 hi = (f16)v;
        sm.s2.gH[row][col] = hi;
        sm.s2.gL[row][col] = (f16)(v - (float)hi);
      }
    }
  }
  __syncthreads();

  // ---- dense: K = [x(rm global) | g1(LDS) | g2(LDS)], W from global ----
  constexpr int CFW = GATE ? 4 : 2;
  f32x4 accD[CFW] = {};
  const long long grow0 = bNN + rows0 + w4*16;
  const f16* xrH = XiRH + (grow0 + lr)*XS;
  const f16* xrL = XiRL + (grow0 + lr)*XS;
  #pragma unroll
  for (int c = 0; c < 15; ++c) {
    f16x4 a_h, a_l;
    if (c < 5) {
      a_h = *(const f16x4*)&xrH[c*16 + 4*lg];
      a_l = *(const f16x4*)&xrL[c*16 + 4*lg];
    } else {
      int gk = (c-5)*16 + 4*lg;
      a_h = *(const f16x4*)&sm.s2.gH[w4*16 + lr][gk];
      a_l = *(const f16x4*)&sm.s2.gL[w4*16 + lr][gk];
    }
    #pragma unroll
    for (int cf = 0; cf < CFW; ++cf) {
      int o = (grp*CFW + cf)*16 + lr;
      f16x4 b_h = *(const f16x4*)&WH[(long long)o*KD + c*16 + 4*lg];
      f16x4 b_l = *(const f16x4*)&WL[(long long)o*KD + c*16 + 4*lg];
      accD[cf] = MFMA16(a_h, b_h, accD[cf]);
      accD[cf] = MFMA16(a_h, b_l, accD[cf]);
      accD[cf] = MFMA16(a_l, b_h, accD[cf]);
    }
  }

  // ---- epilogue ----
  if constexpr (GATE) {
    #pragma unroll
    for (int cf = 0; cf < CFW; ++cf) {
      int o = (grp*CFW + cf)*16 + lr;
      float bi = bias[o];
      #pragma unroll
      for (int reg = 0; reg < 4; ++reg) {
        long long grow = grow0 + lg*4 + reg;
        float v = 1.f/(1.f + expf(-(accD[cf][reg] + bi)));
        if (grp == 0) {
          float zh = v * hbuf[grow*HH + o];
          f16 hi = (f16)zh; f16 lo = (f16)(zh - (float)hi);
          XoRH[grow*XS + ns + o] = hi; XoRL[grow*XS + ns + o] = lo;
          XoCH[(long long)(ns+o)*RS + grow] = hi; XoCL[(long long)(ns+o)*RS + grow] = lo;
        } else {
          rb[grow*HH + (o - HH)] = v;
        }
      }
    }
    if (grp == 0 && lr < ns) {
      #pragma unroll
      for (int reg = 0; reg < 4; ++reg) {
        long long grow = grow0 + lg*4 + reg;
        f16 vh = XiRH[grow*XS + lr], vl = XiRL[grow*XS + lr];
        XoRH[grow*XS + lr] = vh; XoRL[grow*XS + lr] = vl;
        XoCH[(long long)lr*RS + grow] = vh; XoCL[(long long)lr*RS + grow] = vl;
      }
    }
  } else {
    float gop[4] = {0.f,0.f,0.f,0.f};
    #pragma unroll
    for (int cf = 0; cf < CFW; ++cf) {
      int o = (grp*CFW + cf)*16 + lr;
      float bi = bias[o];
      float pwv = 0.f;
      if constexpr (DEC) pwv = pWv[o];
      #pragma unroll
      for (int reg = 0; reg < 4; ++reg) {
        long long grow = grow0 + lg*4 + reg;
        float hc = tanhf(accD[cf][reg] + bi);
        float rv = rb[grow*HH + o];
        float hv = hbuf[grow*HH + o];
        float hn = rv*hv + (1.f - rv)*hc;
        hbuf[grow*HH + o] = hn;
        if (writeX) {
          f16 hi = (f16)hn; f16 lo = (f16)(hn - (float)hi);
          XoRH[grow*XS + ns_next + o] = hi; XoRL[grow*XS + ns_next + o] = lo;
          XoCH[(long long)(ns_next+o)*RS + grow] = hi; XoCL[(long long)(ns_next+o)*RS + grow] = lo;
        }
        if constexpr (DEC) gop[reg] += hn * pwv;
      }
    }
    if constexpr (DEC) {
      #pragma unroll
      for (int reg = 0; reg < 4; ++reg) {
        #pragma unroll
        for (int off = 8; off >= 1; off >>= 1)
          gop[reg] += __shfl_xor(gop[reg], off, 64);
      }
      if (grp == 1 && lr == 0) {
        #pragma unroll
        for (int reg = 0; reg < 4; ++reg)
          gpart[w4*16 + lg*4 + reg] = gop[reg];
      }
      __syncthreads();
      if (grp == 0 && lr == 0) {
        float pb0 = pbv[0];
        #pragma unroll
        for (int reg = 0; reg < 4; ++reg) {
          int n = rows0 + w4*16 + lg*4 + reg;
          long long grow = bNN + n;
          float go = gop[reg] + gpart[w4*16 + lg*4 + reg] + pb0;
          outp[((long long)b*TT + t)*NN + n] = go;
          if (writeX) {
            f16 hi = (f16)go; f16 lo = (f16)(go - (float)hi);
            XoRH[grow*XS] = hi; XoRL[grow*XS] = lo;
            XoCH[grow] = hi; XoCL[grow] = lo;
            float yv = s1src[(long long)b*TTNN + n];
            f16 hy = (f16)yv; f16 ly = (f16)(yv - (float)hy);
            XoRH[grow*XS + 1] = hy; XoRL[grow*XS + 1] = ly;
            XoCH[RS + grow] = hy; XoCL[RS + grow] = ly;
          }
        }
      }
    } else {
      if (writeX && grp == 0 && lr == 0) {
        #pragma unroll
        for (int reg = 0; reg < 4; ++reg) {
          int n = rows0 + w4*16 + lg*4 + reg;
          long long grow = bNN + n;
          float v0 = s0src ? s0src[(long long)b*TTNN + n] : 0.f;
          f16 h0 = (f16)v0; f16 l0 = (f16)(v0 - (float)h0);
          XoRH[grow*XS] = h0; XoRL[grow*XS] = l0;
          XoCH[grow] = h0; XoCL[grow] = l0;
          if (ns_next == 2 && s1src) {
            float v1 = s1src[(long long)b*TTNN + n];
            f16 h1 = (f16)v1; f16 l1 = (f16)(v1 - (float)h1);
            XoRH[grow*XS + 1] = h1; XoRL[grow*XS + 1] = l1;
            XoCH[RS + grow] = h1; XoCL[RS + grow] = l1;
          }
        }
      }
    }
  }
}

// ---------------- E_dyn = ne + h @ hyper_W + hyper_b -----------------------------
__global__ __launch_bounds__(256) void edyn_k(
    const float* __restrict__ h, const float* __restrict__ ne,
    const float* __restrict__ hW, const float* __restrict__ hb, float* __restrict__ Ed)
{
  int row = blockIdx.x*4 + (threadIdx.x >> 6);
  int lane = threadIdx.x & 63;
  float hv = h[(long long)row*HH + lane];
  float myval = 0.f;
  #pragma unroll
  for (int e = 0; e < EE; ++e) {
    float v = hv * hW[lane*EE + e];
    #pragma unroll
    for (int off = 32; off >= 1; off >>= 1) v += __shfl_xor(v, off, 64);
    if (lane == e) myval = v;
  }
  if (lane < EE) {
    int n = row & 511;
    Ed[(long long)row*EE + lane] = ne[n*EE + lane] + hb[lane] + myval;
  }
}

extern "C" void kernel_launch(void* const* d_in, const int* in_sizes, int n_in,
                              void* d_out, int out_size, void* d_ws, size_t ws_size,
                              hipStream_t stream)
{
  const float* x    = (const float*)d_in[0];
  const float* ycov = (const float*)d_in[1];
  const float* ne   = (const float*)d_in[2];
  const float* egW  = (const float*)d_in[3];
  const float* egb  = (const float*)d_in[4];
  const float* euW  = (const float*)d_in[5];
  const float* eub  = (const float*)d_in[6];
  const float* dgW  = (const float*)d_in[7];
  const float* dgb  = (const float*)d_in[8];
  const float* duW  = (const float*)d_in[9];
  const float* dub  = (const float*)d_in[10];
  const float* pW   = (const float*)d_in[11];
  const float* pb   = (const float*)d_in[12];
  const float* hW   = (const float*)d_in[13];
  const float* hb   = (const float*)d_in[14];
  float* out = (float*)d_out;

  char* p = (char*)d_ws;
  f16* AsH  = (f16*)p; p += (size_t)NN*NN*2;
  f16* AsL  = (f16*)p; p += (size_t)NN*NN*2;
  f16* As2H = (f16*)p; p += (size_t)NN*NN*2;
  f16* As2L = (f16*)p; p += (size_t)NN*NN*2;
  f16* AdH  = (f16*)p; p += (size_t)NB*NN*NN*2;
  f16* AdL  = (f16*)p; p += (size_t)NB*NN*NN*2;
  f16* Ad2H = (f16*)p; p += (size_t)NB*NN*NN*2;
  f16* Ad2L = (f16*)p; p += (size_t)NB*NN*NN*2;
  f16* XaRH = (f16*)p; p += (size_t)RS*XS*2;
  f16* XaRL = (f16*)p; p += (size_t)RS*XS*2;
  f16* XaCH = (f16*)p; p += (size_t)RS*XS*2;
  f16* XaCL = (f16*)p; p += (size_t)RS*XS*2;
  f16* XbRH = (f16*)p; p += (size_t)RS*XS*2;
  f16* XbRL = (f16*)p; p += (size_t)RS*XS*2;
  f16* XbCH = (f16*)p; p += (size_t)RS*XS*2;
  f16* XbCL = (f16*)p; p += (size_t)RS*XS*2;
  float* h  = (float*)p; p += (size_t)RS*HH*4;
  float* rb = (float*)p; p += (size_t)RS*HH*4;
  float* Ed = (float*)p; p += (size_t)RS*EE*4;
  f16* WgeH = (f16*)p; p += (size_t)128*KD*2;
  f16* WgeL = (f16*)p; p += (size_t)128*KD*2;
  f16* WueH = (f16*)p; p += (size_t)64*KD*2;
  f16* WueL = (f16*)p; p += (size_t)64*KD*2;
  f16* WgdH = (f16*)p; p += (size_t)128*KD*2;
  f16* WgdL = (f16*)p; p += (size_t)128*KD*2;
  f16* WudH = (f16*)p; p += (size_t)64*KD*2;
  f16* WudL = (f16*)p; p += (size_t)64*KD*2;

  fold_w_t<<<(128*KD+255)/256, 256, 0, stream>>>(egW, WgeH, WgeL, 65, 128);
  fold_w_t<<<(64*KD +255)/256, 256, 0, stream>>>(euW, WueH, WueL, 65, 64);
  fold_w_t<<<(128*KD+255)/256, 256, 0, stream>>>(dgW, WgdH, WgdL, 66, 128);
  fold_w_t<<<(64*KD +255)/256, 256, 0, stream>>>(duW, WudH, WudL, 66, 64);

  softmax_graph<<<64, 512, 0, stream>>>(ne, 0, AsH, AsL, 0);
  sq_mm<<<dim3(8,8,1), 256, 0, stream>>>(AsH, AsL, 0, As2H, As2L, 0);
  (void)hipMemsetAsync(h, 0, (size_t)RS*HH*4, stream);
  (void)hipMemsetAsync(XaRH, 0, (size_t)RS*XS*2*8, stream);  // all 8 X arrays contiguous
  fill_col<<<(RS+255)/256, 256, 0, stream>>>(XaRH, XaRL, XaCH, XaCL, 0, x, (long long)TTNN);

  dim3 fgrid(NB, 8);
  for (int t = 0; t < TT; ++t) {
    fused_half<1,0><<<fgrid, 512, 0, stream>>>(
        AsH, AsL, As2H, As2L, 0,
        XaRH, XaRL, XaCH, XaCL, XbRH, XbRL, XbCH, XbCL,
        WgeH, WgeL, egb, h, rb, nullptr, nullptr, nullptr, t,
        nullptr, nullptr, 1, 0, 1);
    fused_half<0,0><<<fgrid, 512, 0, stream>>>(
        AsH, AsL, As2H, As2L, 0,
        XbRH, XbRL, XbCH, XbCL, XaRH, XaRL, XaCH, XaCL,
        WueH, WueL, eub, h, rb, nullptr, nullptr, nullptr, t,
        (t < TT-1 ? x + (size_t)(t+1)*NN : nullptr),
        (t < TT-1 ? nullptr : ycov),
        1, (t < TT-1 ? 1 : 2), 1);
  }

  edyn_k<<<RS/4, 256, 0, stream>>>(h, ne, hW, hb, Ed);
  softmax_graph<<<NB*64, 512, 0, stream>>>(Ed, (long long)NN*EE, AdH, AdL, (long long)NN*NN);
  sq_mm<<<dim3(8,8,NB), 256, 0, stream>>>(AdH, AdL, (long long)NN*NN, Ad2H, Ad2L, (long long)NN*NN);

  for (int t = 0; t < TT; ++t) {
    fused_half<1,0><<<fgrid, 512, 0, stream>>>(
        AdH, AdL, Ad2H, Ad2L, (long long)NN*NN,
        XaRH, XaRL, XaCH, XaCL, XbRH, XbRL, XbCH, XbCL,
        WgdH, WgdL, dgb, h, rb, nullptr, nullptr, nullptr, t,
        nullptr, nullptr, 2, 0, 1);
    fused_half<0,1><<<fgrid, 512, 0, stream>>>(
        AdH, AdL, Ad2H, Ad2L, (long long)NN*NN,
        XbRH, XbRL, XbCH, XbCL, XaRH, XaRL, XaCH, XaCL,
        WudH, WudL, dub, h, rb, pW, pb, out, t,
        nullptr, (t < TT-1 ? ycov + (size_t)(t+1)*NN : nullptr),
        2, 2, (t < TT-1 ? 1 : 0));
  }
}